// Round 7
// baseline (224.113 us; speedup 1.0000x reference)
//
#include <hip/hip_runtime.h>

#define B_ 2
#define S_ 2048
#define D_ 1024
#define H_ 16
#define DH_ 64
#define WIN_ 256

typedef __attribute__((ext_vector_type(8))) short bf16x8;
typedef __attribute__((ext_vector_type(4))) float f32x4;
typedef unsigned short u16;

#define MFMA(a, b, c) __builtin_amdgcn_mfma_f32_16x16x32_bf16((a), (b), (c), 0, 0, 0)

__device__ __forceinline__ u16 f2b(float f) {
  unsigned int u = __float_as_uint(f);
  u += 0x7fffu + ((u >> 16) & 1u);
  return (u16)(u >> 16);
}

__device__ __forceinline__ float b2f(u16 b) {
  return __uint_as_float(((unsigned int)b) << 16);
}

__device__ __forceinline__ void async_cp16(const void* g, void* l) {
  __builtin_amdgcn_global_load_lds(
      (const __attribute__((address_space(1))) void*)g,
      (__attribute__((address_space(3))) void*)l, 16, 0, 0);
}

// ------- prep: x fp32->bf16 convert (blocks 0..4095) + weight transpose -------
__global__ void k_prep(const float* __restrict__ x,
                       const float* __restrict__ wq, const float* __restrict__ wk,
                       const float* __restrict__ wv, const float* __restrict__ wo,
                       u16* __restrict__ xb, u16* __restrict__ wqkvt, u16* __restrict__ wot) {
  __shared__ float tile[64][65];
  const int bx = blockIdx.x;
  const int t = threadIdx.x;
  if (bx < 4096) {
    int i = (bx * 256 + t) * 4;
    float4 v = *(const float4*)(x + i);
    ushort4 o;
    o.x = f2b(v.x); o.y = f2b(v.y); o.z = f2b(v.z); o.w = f2b(v.w);
    *(ushort4*)(xb + i) = o;
    return;
  }
  const int tb = bx - 4096;
  const int z = tb >> 8, rest = tb & 255;
  const float* W = z == 0 ? wq : z == 1 ? wk : z == 2 ? wv : wo;
  u16* T = z < 3 ? wqkvt + (size_t)z * 1024 * 1024 : wot;
  const int bn = (rest & 15) * 64;   // col block of W = row block of T
  const int bk = (rest >> 4) * 64;   // row block of W
  const int r = t >> 4;
  const int c = (t & 15) * 4;
#pragma unroll
  for (int i = 0; i < 4; i++) {
    float4 v = *(const float4*)(W + (size_t)(bk + r + i * 16) * D_ + bn + c);
    tile[c + 0][r + i * 16] = v.x;
    tile[c + 1][r + i * 16] = v.y;
    tile[c + 2][r + i * 16] = v.z;
    tile[c + 3][r + i * 16] = v.w;
  }
  __syncthreads();
  const int n = t >> 2, seg = (t & 3) * 16;
  __align__(16) u16 tmp[16];
#pragma unroll
  for (int u = 0; u < 16; u++) tmp[u] = f2b(tile[n][seg + u]);
  uint4* dst = (uint4*)(T + (size_t)(bn + n) * D_ + bk + seg);
  dst[0] = ((uint4*)tmp)[0];
  dst[1] = ((uint4*)tmp)[1];
}

// ---------------- 128x128 GEMM core, BK=64, XOR bank swizzle ----------------
__device__ __forceinline__ void gemm_core128(const u16* __restrict__ Ag, const u16* __restrict__ Btg,
                                             u16* As, u16* Bs, f32x4 (&acc)[4][4],
                                             int m0, int n0) {
  const int tid = threadIdx.x;
  const int w = tid >> 6, lane = tid & 63;
  const int quad = lane >> 4, l15 = lane & 15;
  const int wm = (w & 1) * 64, wn = (w >> 1) * 64;
  const int rowa = tid >> 3;                       // 0..31
  const int colsw = (((tid & 7) ^ (rowa & 7)) * 8);
  const u16* ap = Ag + (size_t)(m0 + rowa) * D_ + colsw;
  const u16* bp = Btg + (size_t)(n0 + rowa) * D_ + colsw;
  u16* As0 = As + w * 512;
  u16* Bs0 = Bs + w * 512;
  const int c0 = ((quad * 8) ^ ((l15 & 7) * 8));
  for (int kb = 0; kb < D_; kb += 64) {
#pragma unroll
    for (int i = 0; i < 4; i++) {
      async_cp16(ap + kb + (size_t)(i * 32) * D_, As0 + i * 2048);
      async_cp16(bp + kb + (size_t)(i * 32) * D_, Bs0 + i * 2048);
    }
    __syncthreads();
#pragma unroll
    for (int kh = 0; kh < 2; kh++) {
      const int c = c0 ^ (kh * 32);
      bf16x8 af[4], bfr[4];
#pragma unroll
      for (int i = 0; i < 4; i++) af[i] = *(const bf16x8*)&As[(wm + i * 16 + l15) * 64 + c];
#pragma unroll
      for (int j = 0; j < 4; j++) bfr[j] = *(const bf16x8*)&Bs[(wn + j * 16 + l15) * 64 + c];
#pragma unroll
      for (int i = 0; i < 4; i++)
#pragma unroll
        for (int j = 0; j < 4; j++) acc[i][j] = MFMA(af[i], bfr[j], acc[i][j]);
    }
    __syncthreads();
  }
}

// -------- fused QKV GEMM over N=3072; Q,K -> [B,S,D]; V -> [B,H,DH,S] --------
__global__ __launch_bounds__(256, 3) void k_gemm_qkv(
    const u16* __restrict__ xb, const u16* __restrict__ wqkvt,
    const float* __restrict__ bq, const float* __restrict__ bk_, const float* __restrict__ bv,
    u16* __restrict__ Qg, u16* __restrict__ Kg, u16* __restrict__ Vt) {
  __shared__ __align__(16) u16 smem[17408];   // stage: 2x8192; epilogue: 128x136
  u16* As = smem;
  u16* Bs = smem + 8192;
  const int L = blockIdx.x;
  const int xcd = L & 7, slot = L >> 3;            // slot 0..95
  const int mblk = (xcd >> 1) * 8 + (slot & 7);    // 0..31
  const int nblk = (xcd & 1) * 12 + (slot >> 3);   // 0..23
  const int n0 = nblk * 128, m0 = mblk * 128;
  const int z = n0 >> 10;
  const float* bias = z == 0 ? bq : z == 1 ? bk_ : bv;
  f32x4 acc[4][4] = {};
  gemm_core128(xb, wqkvt, As, Bs, acc, m0, n0);

  const int tid = threadIdx.x;
  const int w = tid >> 6, lane = tid & 63;
  const int quad = lane >> 4, l15 = lane & 15;
  const int wm = (w & 1) * 64, wn = (w >> 1) * 64;
  const int nloc = n0 & 1023;
  float biasv[4];
#pragma unroll
  for (int j = 0; j < 4; j++) biasv[j] = bias[nloc + wn + j * 16 + l15];
  const int b_ = m0 >> 11, sb = m0 & 2047;
  // Q pre-scale folds 1/sqrt(DH) and log2(e) so attention uses raw exp2.
  const float scale = z == 0 ? 0.125f * 1.44269504f : 1.0f;
  const int row = tid >> 4, ch = tid & 15;

  if (z < 2) {
    // C-layout -> LDS (padded stride 136) -> coalesced row-major store
#pragma unroll
    for (int j = 0; j < 4; j++)
#pragma unroll
      for (int i = 0; i < 4; i++)
#pragma unroll
        for (int r = 0; r < 4; r++)
          smem[(wm + i * 16 + quad * 4 + r) * 136 + wn + j * 16 + l15] =
              f2b((acc[i][j][r] + biasv[j]) * scale);
    __syncthreads();
    u16* OG = z == 0 ? Qg : Kg;
#pragma unroll
    for (int it = 0; it < 8; it++) {
      int rr = row + it * 16;
      bf16x8 v = *(const bf16x8*)&smem[rr * 136 + ch * 8];
      *(bf16x8*)(OG + (size_t)(m0 + rr) * D_ + nloc + ch * 8) = v;
    }
  } else {
    // write transposed into LDS: Ct[n_local][m_local]
#pragma unroll
    for (int j = 0; j < 4; j++)
#pragma unroll
      for (int i = 0; i < 4; i++)
#pragma unroll
        for (int r = 0; r < 4; r++)
          smem[(wn + j * 16 + l15) * 136 + wm + i * 16 + quad * 4 + r] =
              f2b(acc[i][j][r] + biasv[j]);
    __syncthreads();
#pragma unroll
    for (int it = 0; it < 8; it++) {
      int nn = nloc + row + it * 16;
      int h = nn >> 6, dh = nn & 63;
      bf16x8 v = *(const bf16x8*)&smem[(row + it * 16) * 136 + ch * 8];
      *(bf16x8*)(Vt + ((size_t)(b_ * H_ + h) * DH_ + dh) * S_ + sb + ch * 8) = v;
    }
  }
}

// ---------- output projection: 64x128 tiles, 1D grid 512, XCD-aware ----------
__global__ __launch_bounds__(256, 2) void k_gemm_out(
    const u16* __restrict__ Ab, const u16* __restrict__ wot,
    const float* __restrict__ bo, float* __restrict__ out) {
  __shared__ __align__(16) u16 smem[12288];   // stage: 4096 + 8192; epilogue: 64x136
  u16* As = smem;
  u16* Bs = smem + 4096;
  const int L = blockIdx.x;
  const int xcd = L & 7, slot = L >> 3;        // slot 0..63
  const int mblk = xcd * 8 + (slot & 7);       // 0..63
  const int nblk = slot >> 3;                  // 0..7
  const int n0 = nblk * 128, m0 = mblk * 64;
  const int tid = threadIdx.x;
  const int w = tid >> 6, lane = tid & 63;
  const int quad = lane >> 4, l15 = lane & 15;
  const int wn = w * 32;
  const int rowa = tid >> 3;
  const int colsw = (((tid & 7) ^ (rowa & 7)) * 8);
  const u16* ap = Ab + (size_t)(m0 + rowa) * D_ + colsw;
  const u16* bp = wot + (size_t)(n0 + rowa) * D_ + colsw;
  u16* As0 = As + w * 512;
  u16* Bs0 = Bs + w * 512;
  const int c0 = ((quad * 8) ^ ((l15 & 7) * 8));
  f32x4 acc[4][2] = {};
  for (int kb = 0; kb < D_; kb += 64) {
#pragma unroll
    for (int i = 0; i < 2; i++)
      async_cp16(ap + kb + (size_t)(i * 32) * D_, As0 + i * 2048);
#pragma unroll
    for (int i = 0; i < 4; i++)
      async_cp16(bp + kb + (size_t)(i * 32) * D_, Bs0 + i * 2048);
    __syncthreads();
#pragma unroll
    for (int kh = 0; kh < 2; kh++) {
      const int c = c0 ^ (kh * 32);
      bf16x8 af[4], bfr[2];
#pragma unroll
      for (int i = 0; i < 4; i++) af[i] = *(const bf16x8*)&As[(i * 16 + l15) * 64 + c];
#pragma unroll
      for (int j = 0; j < 2; j++) bfr[j] = *(const bf16x8*)&Bs[(wn + j * 16 + l15) * 64 + c];
#pragma unroll
      for (int i = 0; i < 4; i++)
#pragma unroll
        for (int j = 0; j < 2; j++) acc[i][j] = MFMA(af[i], bfr[j], acc[i][j]);
    }
    __syncthreads();
  }
  float biasv[2];
#pragma unroll
  for (int j = 0; j < 2; j++) biasv[j] = bo[n0 + wn + j * 16 + l15];
#pragma unroll
  for (int j = 0; j < 2; j++)
#pragma unroll
    for (int i = 0; i < 4; i++)
#pragma unroll
      for (int r = 0; r < 4; r++)
        smem[(i * 16 + quad * 4 + r) * 136 + wn + j * 16 + l15] = f2b(acc[i][j][r] + biasv[j]);
  __syncthreads();
  const int row = tid >> 4, ch = tid & 15;
#pragma unroll
  for (int it = 0; it < 4; it++) {
    int rr = row + it * 16;
    bf16x8 v = *(const bf16x8*)&smem[rr * 136 + ch * 8];
    float4 f0, f1;
    f0.x = b2f((u16)v[0]); f0.y = b2f((u16)v[1]); f0.z = b2f((u16)v[2]); f0.w = b2f((u16)v[3]);
    f1.x = b2f((u16)v[4]); f1.y = b2f((u16)v[5]); f1.z = b2f((u16)v[6]); f1.w = b2f((u16)v[7]);
    float* dst = out + (size_t)(m0 + rr) * D_ + n0 + ch * 8;
    *(float4*)dst = f0;
    *(float4*)(dst + 4) = f1;
  }
}

// ---------------- windowed flash attention, static softmax ----------------
__global__ __launch_bounds__(256, 4) void k_attn(
    const u16* __restrict__ Qg, const u16* __restrict__ Kg,
    const u16* __restrict__ Vt, u16* __restrict__ Ab) {
  __shared__ __align__(16) u16 Plds[4][16 * 72];   // stride 72 breaks bank aliasing
  const int tid = threadIdx.x;
  const int w = tid >> 6, lane = tid & 63;
  const int quad = lane >> 4, l15 = lane & 15;
  const int bh = blockIdx.x;
  const int qw = blockIdx.y * 64 + w * 16;
  const int b_ = bh >> 4, h = bh & 15;

  const u16* Qbase = Qg + (size_t)(b_ * S_ + qw + l15) * D_ + h * DH_ + quad * 8;
  bf16x8 aq0 = *(const bf16x8*)Qbase;
  bf16x8 aq1 = *(const bf16x8*)(Qbase + 32);

  float lr[4] = {0.f, 0.f, 0.f, 0.f};
  f32x4 Oacc[4] = {};

  const u16* Kb = Kg + (size_t)b_ * S_ * D_ + h * DH_;
  const u16* Vb = Vt + (size_t)bh * DH_ * S_;
  const int klo = qw >= WIN_ ? ((qw - WIN_) & ~31) : 0;
  u16* P = &Plds[w][0];

  for (int k0 = klo; k0 < qw + 16; k0 += 32) {
    const u16* Kt0 = Kb + (size_t)(k0 + l15) * D_ + quad * 8;
    bf16x8 b00 = *(const bf16x8*)Kt0;
    bf16x8 b01 = *(const bf16x8*)(Kt0 + 32);
    bf16x8 b10 = *(const bf16x8*)(Kt0 + (size_t)16 * D_);
    bf16x8 b11 = *(const bf16x8*)(Kt0 + (size_t)16 * D_ + 32);
    f32x4 s0 = {0.f, 0.f, 0.f, 0.f}, s1 = {0.f, 0.f, 0.f, 0.f};
    s0 = MFMA(aq0, b00, s0);
    s0 = MFMA(aq1, b01, s0);
    s1 = MFMA(aq0, b10, s1);
    s1 = MFMA(aq1, b11, s1);

    const int key0 = k0 + l15, key1 = k0 + 16 + l15;
#pragma unroll
    for (int r = 0; r < 4; r++) {
      int q = qw + quad * 4 + r;
      float p0 = (key0 <= q && key0 + WIN_ >= q) ? __builtin_amdgcn_exp2f(s0[r]) : 0.f;
      float p1 = (key1 <= q && key1 + WIN_ >= q) ? __builtin_amdgcn_exp2f(s1[r]) : 0.f;
      s0[r] = p0; s1[r] = p1;
      lr[r] += p0 + p1;
    }
    // C-layout -> LDS -> A-layout (wave-private)
    asm volatile("s_waitcnt lgkmcnt(0)" ::: "memory");
#pragma unroll
    for (int r = 0; r < 4; r++) {
      P[(quad * 4 + r) * 72 + l15] = f2b(s0[r]);
      P[(quad * 4 + r) * 72 + 16 + l15] = f2b(s1[r]);
    }
    asm volatile("s_waitcnt lgkmcnt(0)" ::: "memory");
    bf16x8 apf = *(const bf16x8*)&P[l15 * 72 + quad * 8];
#pragma unroll
    for (int j = 0; j < 4; j++) {
      bf16x8 bv = *(const bf16x8*)(Vb + (size_t)(j * 16 + l15) * S_ + k0 + quad * 8);
      Oacc[j] = MFMA(apf, bv, Oacc[j]);
    }
  }

#pragma unroll
  for (int off = 1; off < 16; off <<= 1)
#pragma unroll
    for (int r = 0; r < 4; r++) lr[r] += __shfl_xor(lr[r], off);
  float inv[4];
#pragma unroll
  for (int r = 0; r < 4; r++) inv[r] = 1.0f / lr[r];

  // O: C-layout -> wave LDS -> two coalesced bf16x8 stores per lane (full 16x64)
  asm volatile("s_waitcnt lgkmcnt(0)" ::: "memory");
#pragma unroll
  for (int j = 0; j < 4; j++)
#pragma unroll
    for (int r = 0; r < 4; r++)
      P[(quad * 4 + r) * 72 + j * 16 + l15] = f2b(Oacc[j][r] * inv[r]);
  asm volatile("s_waitcnt lgkmcnt(0)" ::: "memory");
  {
    int rq = lane >> 2, cc = lane & 3;
    bf16x8 v0 = *(const bf16x8*)&P[rq * 72 + cc * 16];
    bf16x8 v1 = *(const bf16x8*)&P[rq * 72 + cc * 16 + 8];
    u16* dst = Ab + (size_t)(b_ * S_ + qw + rq) * D_ + h * DH_ + cc * 16;
    *(bf16x8*)dst = v0;
    *(bf16x8*)(dst + 8) = v1;
  }
}

extern "C" void kernel_launch(void* const* d_in, const int* in_sizes, int n_in,
                              void* d_out, int out_size, void* d_ws, size_t ws_size,
                              hipStream_t stream) {
  const float* x  = (const float*)d_in[0];
  const float* wq = (const float*)d_in[1];
  const float* bq = (const float*)d_in[2];
  const float* wk = (const float*)d_in[3];
  const float* bk = (const float*)d_in[4];
  const float* wv = (const float*)d_in[5];
  const float* bv = (const float*)d_in[6];
  const float* wo = (const float*)d_in[7];
  const float* bo = (const float*)d_in[8];

  char* ws = (char*)d_ws;
  const size_t MB = 1u << 20;
  u16* Qg    = (u16*)(ws + 0 * MB);    // 8 MB [B,S,D] bf16, pre-scaled
  u16* Kg    = (u16*)(ws + 8 * MB);    // 8 MB [B,S,D]
  u16* Vt    = (u16*)(ws + 16 * MB);   // 8 MB [B,H,DH,S]
  u16* Ab    = (u16*)(ws + 24 * MB);   // 8 MB [B,S,D] attention output
  u16* xb    = (u16*)(ws + 32 * MB);   // 8 MB [B*S,D]
  u16* wqkvt = (u16*)(ws + 40 * MB);   // 6 MB [3072][1024] transposed bf16
  u16* wot   = (u16*)(ws + 46 * MB);   // 2 MB [1024][1024] transposed bf16

  k_prep<<<5120, 256, 0, stream>>>(x, wq, wk, wv, wo, xb, wqkvt, wot);
  k_gemm_qkv<<<768, 256, 0, stream>>>(xb, wqkvt, bq, bk, bv, Qg, Kg, Vt);
  // ATTRIBUTION PROBE #2: attn and out each launched twice (idempotent pure
  // functions). dur delta vs round 5 (175.2) == attn_dur + out_dur.
  k_attn<<<dim3(32, 32), 256, 0, stream>>>(Qg, Kg, Vt, Ab);
  k_attn<<<dim3(32, 32), 256, 0, stream>>>(Qg, Kg, Vt, Ab);
  k_gemm_out<<<512, 256, 0, stream>>>(Ab, wot, bo, (float*)d_out);
  k_gemm_out<<<512, 256, 0, stream>>>(Ab, wot, bo, (float*)d_out);
}

// Round 8
// 171.117 us; speedup vs baseline: 1.3097x; 1.3097x over previous
//
#include <hip/hip_runtime.h>

#define B_ 2
#define S_ 2048
#define D_ 1024
#define H_ 16
#define DH_ 64
#define WIN_ 256
#define VTS 2080   // Vt row stride (elements): 4KB+64B breaks L1 set-aliasing

typedef __attribute__((ext_vector_type(8))) short bf16x8;
typedef __attribute__((ext_vector_type(4))) float f32x4;
typedef unsigned short u16;

#define MFMA(a, b, c) __builtin_amdgcn_mfma_f32_16x16x32_bf16((a), (b), (c), 0, 0, 0)

__device__ __forceinline__ u16 f2b(float f) {
  unsigned int u = __float_as_uint(f);
  u += 0x7fffu + ((u >> 16) & 1u);
  return (u16)(u >> 16);
}

__device__ __forceinline__ float b2f(u16 b) {
  return __uint_as_float(((unsigned int)b) << 16);
}

__device__ __forceinline__ void async_cp16(const void* g, void* l) {
  __builtin_amdgcn_global_load_lds(
      (const __attribute__((address_space(1))) void*)g,
      (__attribute__((address_space(3))) void*)l, 16, 0, 0);
}

// ------- prep: x fp32->bf16 convert (blocks 0..4095) + weight transpose -------
__global__ void k_prep(const float* __restrict__ x,
                       const float* __restrict__ wq, const float* __restrict__ wk,
                       const float* __restrict__ wv, const float* __restrict__ wo,
                       u16* __restrict__ xb, u16* __restrict__ wqkvt, u16* __restrict__ wot) {
  __shared__ float tile[64][65];
  const int bx = blockIdx.x;
  const int t = threadIdx.x;
  if (bx < 4096) {
    int i = (bx * 256 + t) * 4;
    float4 v = *(const float4*)(x + i);
    ushort4 o;
    o.x = f2b(v.x); o.y = f2b(v.y); o.z = f2b(v.z); o.w = f2b(v.w);
    *(ushort4*)(xb + i) = o;
    return;
  }
  const int tb = bx - 4096;
  const int z = tb >> 8, rest = tb & 255;
  const float* W = z == 0 ? wq : z == 1 ? wk : z == 2 ? wv : wo;
  u16* T = z < 3 ? wqkvt + (size_t)z * 1024 * 1024 : wot;
  const int bn = (rest & 15) * 64;   // col block of W = row block of T
  const int bk = (rest >> 4) * 64;   // row block of W
  const int r = t >> 4;
  const int c = (t & 15) * 4;
#pragma unroll
  for (int i = 0; i < 4; i++) {
    float4 v = *(const float4*)(W + (size_t)(bk + r + i * 16) * D_ + bn + c);
    tile[c + 0][r + i * 16] = v.x;
    tile[c + 1][r + i * 16] = v.y;
    tile[c + 2][r + i * 16] = v.z;
    tile[c + 3][r + i * 16] = v.w;
  }
  __syncthreads();
  const int n = t >> 2, seg = (t & 3) * 16;
  __align__(16) u16 tmp[16];
#pragma unroll
  for (int u = 0; u < 16; u++) tmp[u] = f2b(tile[n][seg + u]);
  uint4* dst = (uint4*)(T + (size_t)(bn + n) * D_ + bk + seg);
  dst[0] = ((uint4*)tmp)[0];
  dst[1] = ((uint4*)tmp)[1];
}

// ---------------- 128x128 GEMM core, BK=64, XOR bank swizzle ----------------
__device__ __forceinline__ void gemm_core128(const u16* __restrict__ Ag, const u16* __restrict__ Btg,
                                             u16* As, u16* Bs, f32x4 (&acc)[4][4],
                                             int m0, int n0) {
  const int tid = threadIdx.x;
  const int w = tid >> 6, lane = tid & 63;
  const int quad = lane >> 4, l15 = lane & 15;
  const int wm = (w & 1) * 64, wn = (w >> 1) * 64;
  const int rowa = tid >> 3;                       // 0..31
  const int colsw = (((tid & 7) ^ (rowa & 7)) * 8);
  const u16* ap = Ag + (size_t)(m0 + rowa) * D_ + colsw;
  const u16* bp = Btg + (size_t)(n0 + rowa) * D_ + colsw;
  u16* As0 = As + w * 512;
  u16* Bs0 = Bs + w * 512;
  const int c0 = ((quad * 8) ^ ((l15 & 7) * 8));
  for (int kb = 0; kb < D_; kb += 64) {
#pragma unroll
    for (int i = 0; i < 4; i++) {
      async_cp16(ap + kb + (size_t)(i * 32) * D_, As0 + i * 2048);
      async_cp16(bp + kb + (size_t)(i * 32) * D_, Bs0 + i * 2048);
    }
    __syncthreads();
#pragma unroll
    for (int kh = 0; kh < 2; kh++) {
      const int c = c0 ^ (kh * 32);
      bf16x8 af[4], bfr[4];
#pragma unroll
      for (int i = 0; i < 4; i++) af[i] = *(const bf16x8*)&As[(wm + i * 16 + l15) * 64 + c];
#pragma unroll
      for (int j = 0; j < 4; j++) bfr[j] = *(const bf16x8*)&Bs[(wn + j * 16 + l15) * 64 + c];
#pragma unroll
      for (int i = 0; i < 4; i++)
#pragma unroll
        for (int j = 0; j < 4; j++) acc[i][j] = MFMA(af[i], bfr[j], acc[i][j]);
    }
    __syncthreads();
  }
}

// -------- fused QKV GEMM over N=3072; Q,K -> [B,S,D]; V -> [B,H,DH,VTS] --------
__global__ __launch_bounds__(256, 3) void k_gemm_qkv(
    const u16* __restrict__ xb, const u16* __restrict__ wqkvt,
    const float* __restrict__ bq, const float* __restrict__ bk_, const float* __restrict__ bv,
    u16* __restrict__ Qg, u16* __restrict__ Kg, u16* __restrict__ Vt) {
  __shared__ __align__(16) u16 smem[17408];   // stage: 2x8192; epilogue: 128x136
  u16* As = smem;
  u16* Bs = smem + 8192;
  const int L = blockIdx.x;
  const int xcd = L & 7, slot = L >> 3;            // slot 0..95
  const int mblk = (xcd >> 1) * 8 + (slot & 7);    // 0..31
  const int nblk = (xcd & 1) * 12 + (slot >> 3);   // 0..23
  const int n0 = nblk * 128, m0 = mblk * 128;
  const int z = n0 >> 10;
  const float* bias = z == 0 ? bq : z == 1 ? bk_ : bv;
  f32x4 acc[4][4] = {};
  gemm_core128(xb, wqkvt, As, Bs, acc, m0, n0);

  const int tid = threadIdx.x;
  const int w = tid >> 6, lane = tid & 63;
  const int quad = lane >> 4, l15 = lane & 15;
  const int wm = (w & 1) * 64, wn = (w >> 1) * 64;
  const int nloc = n0 & 1023;
  float biasv[4];
#pragma unroll
  for (int j = 0; j < 4; j++) biasv[j] = bias[nloc + wn + j * 16 + l15];
  const int b_ = m0 >> 11, sb = m0 & 2047;
  // Q pre-scale folds 1/sqrt(DH) and log2(e) so attention uses raw exp2.
  const float scale = z == 0 ? 0.125f * 1.44269504f : 1.0f;
  const int row = tid >> 4, ch = tid & 15;

  if (z < 2) {
    // C-layout -> LDS (padded stride 136) -> coalesced row-major store
#pragma unroll
    for (int j = 0; j < 4; j++)
#pragma unroll
      for (int i = 0; i < 4; i++)
#pragma unroll
        for (int r = 0; r < 4; r++)
          smem[(wm + i * 16 + quad * 4 + r) * 136 + wn + j * 16 + l15] =
              f2b((acc[i][j][r] + biasv[j]) * scale);
    __syncthreads();
    u16* OG = z == 0 ? Qg : Kg;
#pragma unroll
    for (int it = 0; it < 8; it++) {
      int rr = row + it * 16;
      bf16x8 v = *(const bf16x8*)&smem[rr * 136 + ch * 8];
      *(bf16x8*)(OG + (size_t)(m0 + rr) * D_ + nloc + ch * 8) = v;
    }
  } else {
    // write transposed into LDS: Ct[n_local][m_local]
#pragma unroll
    for (int j = 0; j < 4; j++)
#pragma unroll
      for (int i = 0; i < 4; i++)
#pragma unroll
        for (int r = 0; r < 4; r++)
          smem[(wn + j * 16 + l15) * 136 + wm + i * 16 + quad * 4 + r] =
              f2b(acc[i][j][r] + biasv[j]);
    __syncthreads();
#pragma unroll
    for (int it = 0; it < 8; it++) {
      int nn = nloc + row + it * 16;
      int h = nn >> 6, dh = nn & 63;
      bf16x8 v = *(const bf16x8*)&smem[(row + it * 16) * 136 + ch * 8];
      *(bf16x8*)(Vt + ((size_t)(b_ * H_ + h) * DH_ + dh) * VTS + sb + ch * 8) = v;
    }
  }
}

// ---------- output projection: 64x128 tiles, 1D grid 512, XCD-aware ----------
__global__ __launch_bounds__(256, 2) void k_gemm_out(
    const u16* __restrict__ Ab, const u16* __restrict__ wot,
    const float* __restrict__ bo, float* __restrict__ out) {
  __shared__ __align__(16) u16 smem[12288];   // stage: 4096 + 8192; epilogue: 64x136
  u16* As = smem;
  u16* Bs = smem + 4096;
  const int L = blockIdx.x;
  const int xcd = L & 7, slot = L >> 3;        // slot 0..63
  const int mblk = xcd * 8 + (slot & 7);       // 0..63
  const int nblk = slot >> 3;                  // 0..7
  const int n0 = nblk * 128, m0 = mblk * 64;
  const int tid = threadIdx.x;
  const int w = tid >> 6, lane = tid & 63;
  const int quad = lane >> 4, l15 = lane & 15;
  const int wn = w * 32;
  const int rowa = tid >> 3;
  const int colsw = (((tid & 7) ^ (rowa & 7)) * 8);
  const u16* ap = Ab + (size_t)(m0 + rowa) * D_ + colsw;
  const u16* bp = wot + (size_t)(n0 + rowa) * D_ + colsw;
  u16* As0 = As + w * 512;
  u16* Bs0 = Bs + w * 512;
  const int c0 = ((quad * 8) ^ ((l15 & 7) * 8));
  f32x4 acc[4][2] = {};
  for (int kb = 0; kb < D_; kb += 64) {
#pragma unroll
    for (int i = 0; i < 2; i++)
      async_cp16(ap + kb + (size_t)(i * 32) * D_, As0 + i * 2048);
#pragma unroll
    for (int i = 0; i < 4; i++)
      async_cp16(bp + kb + (size_t)(i * 32) * D_, Bs0 + i * 2048);
    __syncthreads();
#pragma unroll
    for (int kh = 0; kh < 2; kh++) {
      const int c = c0 ^ (kh * 32);
      bf16x8 af[4], bfr[2];
#pragma unroll
      for (int i = 0; i < 4; i++) af[i] = *(const bf16x8*)&As[(i * 16 + l15) * 64 + c];
#pragma unroll
      for (int j = 0; j < 2; j++) bfr[j] = *(const bf16x8*)&Bs[(wn + j * 16 + l15) * 64 + c];
#pragma unroll
      for (int i = 0; i < 4; i++)
#pragma unroll
        for (int j = 0; j < 2; j++) acc[i][j] = MFMA(af[i], bfr[j], acc[i][j]);
    }
    __syncthreads();
  }
  float biasv[2];
#pragma unroll
  for (int j = 0; j < 2; j++) biasv[j] = bo[n0 + wn + j * 16 + l15];
#pragma unroll
  for (int j = 0; j < 2; j++)
#pragma unroll
    for (int i = 0; i < 4; i++)
#pragma unroll
      for (int r = 0; r < 4; r++)
        smem[(i * 16 + quad * 4 + r) * 136 + wn + j * 16 + l15] = f2b(acc[i][j][r] + biasv[j]);
  __syncthreads();
  const int row = tid >> 4, ch = tid & 15;
#pragma unroll
  for (int it = 0; it < 4; it++) {
    int rr = row + it * 16;
    bf16x8 v = *(const bf16x8*)&smem[rr * 136 + ch * 8];
    float4 f0, f1;
    f0.x = b2f((u16)v[0]); f0.y = b2f((u16)v[1]); f0.z = b2f((u16)v[2]); f0.w = b2f((u16)v[3]);
    f1.x = b2f((u16)v[4]); f1.y = b2f((u16)v[5]); f1.z = b2f((u16)v[6]); f1.w = b2f((u16)v[7]);
    float* dst = out + (size_t)(m0 + rr) * D_ + n0 + ch * 8;
    *(float4*)dst = f0;
    *(float4*)(dst + 4) = f1;
  }
}

// ---------------- windowed flash attention, static softmax ----------------
// Q,K in [B,S,D] (Q pre-scaled by 0.125*log2e); Vt in [B,H,DH,VTS]; out Ab [B,S,D].
// R8: K AND V loads hoisted to tile top (V latency overlaps QK/softmax/LDS chain
// instead of serializing after the lgkm barrier); P double-buffered so the only
// LDS drain left is the inherent write->read one.
__global__ __launch_bounds__(256, 4) void k_attn(
    const u16* __restrict__ Qg, const u16* __restrict__ Kg,
    const u16* __restrict__ Vt, u16* __restrict__ Ab) {
  __shared__ __align__(16) u16 Plds[4][2][16 * 72];
  const int tid = threadIdx.x;
  const int w = tid >> 6, lane = tid & 63;
  const int quad = lane >> 4, l15 = lane & 15;
  const int bh = blockIdx.x;
  const int qw = blockIdx.y * 64 + w * 16;
  const int b_ = bh >> 4, h = bh & 15;

  const u16* Qbase = Qg + (size_t)(b_ * S_ + qw + l15) * D_ + h * DH_ + quad * 8;
  bf16x8 aq0 = *(const bf16x8*)Qbase;
  bf16x8 aq1 = *(const bf16x8*)(Qbase + 32);

  float lr[4] = {0.f, 0.f, 0.f, 0.f};
  f32x4 Oacc[4] = {};

  const u16* Kb = Kg + (size_t)b_ * S_ * D_ + h * DH_;
  const u16* Vb = Vt + (size_t)bh * DH_ * VTS;
  const int klo = qw >= WIN_ ? ((qw - WIN_) & ~31) : 0;
  u16* Pb[2] = {&Plds[w][0][0], &Plds[w][1][0]};
  int par = 0;

  for (int k0 = klo; k0 < qw + 16; k0 += 32) {
    // --- issue ALL global loads first (K for QK^T, V for PV) ---
    const u16* Kt0 = Kb + (size_t)(k0 + l15) * D_ + quad * 8;
    bf16x8 b00 = *(const bf16x8*)Kt0;
    bf16x8 b01 = *(const bf16x8*)(Kt0 + 32);
    bf16x8 b10 = *(const bf16x8*)(Kt0 + (size_t)16 * D_);
    bf16x8 b11 = *(const bf16x8*)(Kt0 + (size_t)16 * D_ + 32);
    const u16* Vt0 = Vb + (size_t)l15 * VTS + k0 + quad * 8;
    bf16x8 v0 = *(const bf16x8*)(Vt0);
    bf16x8 v1 = *(const bf16x8*)(Vt0 + (size_t)16 * VTS);
    bf16x8 v2 = *(const bf16x8*)(Vt0 + (size_t)32 * VTS);
    bf16x8 v3 = *(const bf16x8*)(Vt0 + (size_t)48 * VTS);

    f32x4 s0 = {0.f, 0.f, 0.f, 0.f}, s1 = {0.f, 0.f, 0.f, 0.f};
    s0 = MFMA(aq0, b00, s0);
    s0 = MFMA(aq1, b01, s0);
    s1 = MFMA(aq0, b10, s1);
    s1 = MFMA(aq1, b11, s1);

    const int key0 = k0 + l15, key1 = k0 + 16 + l15;
#pragma unroll
    for (int r = 0; r < 4; r++) {
      int q = qw + quad * 4 + r;
      float p0 = (key0 <= q && key0 + WIN_ >= q) ? __builtin_amdgcn_exp2f(s0[r]) : 0.f;
      float p1 = (key1 <= q && key1 + WIN_ >= q) ? __builtin_amdgcn_exp2f(s1[r]) : 0.f;
      s0[r] = p0; s1[r] = p1;
      lr[r] += p0 + p1;
    }
    // C-layout -> LDS -> A-layout (wave-private, double-buffered: no pre-drain)
    u16* P = Pb[par];
#pragma unroll
    for (int r = 0; r < 4; r++) {
      P[(quad * 4 + r) * 72 + l15] = f2b(s0[r]);
      P[(quad * 4 + r) * 72 + 16 + l15] = f2b(s1[r]);
    }
    asm volatile("s_waitcnt lgkmcnt(0)" ::: "memory");
    bf16x8 apf = *(const bf16x8*)&P[l15 * 72 + quad * 8];
    Oacc[0] = MFMA(apf, v0, Oacc[0]);
    Oacc[1] = MFMA(apf, v1, Oacc[1]);
    Oacc[2] = MFMA(apf, v2, Oacc[2]);
    Oacc[3] = MFMA(apf, v3, Oacc[3]);
    par ^= 1;
  }

#pragma unroll
  for (int off = 1; off < 16; off <<= 1)
#pragma unroll
    for (int r = 0; r < 4; r++) lr[r] += __shfl_xor(lr[r], off);
  float inv[4];
#pragma unroll
  for (int r = 0; r < 4; r++) inv[r] = 1.0f / lr[r];

  // O: C-layout -> wave LDS -> two coalesced bf16x8 stores per lane (full 16x64)
  asm volatile("s_waitcnt lgkmcnt(0)" ::: "memory");
  u16* P = Pb[0];
#pragma unroll
  for (int j = 0; j < 4; j++)
#pragma unroll
    for (int r = 0; r < 4; r++)
      P[(quad * 4 + r) * 72 + j * 16 + l15] = f2b(Oacc[j][r] * inv[r]);
  asm volatile("s_waitcnt lgkmcnt(0)" ::: "memory");
  {
    int rq = lane >> 2, cc = lane & 3;
    bf16x8 v0 = *(const bf16x8*)&P[rq * 72 + cc * 16];
    bf16x8 v1 = *(const bf16x8*)&P[rq * 72 + cc * 16 + 8];
    u16* dst = Ab + (size_t)(b_ * S_ + qw + rq) * D_ + h * DH_ + cc * 16;
    *(bf16x8*)dst = v0;
    *(bf16x8*)(dst + 8) = v1;
  }
}

extern "C" void kernel_launch(void* const* d_in, const int* in_sizes, int n_in,
                              void* d_out, int out_size, void* d_ws, size_t ws_size,
                              hipStream_t stream) {
  const float* x  = (const float*)d_in[0];
  const float* wq = (const float*)d_in[1];
  const float* bq = (const float*)d_in[2];
  const float* wk = (const float*)d_in[3];
  const float* bk = (const float*)d_in[4];
  const float* wv = (const float*)d_in[5];
  const float* bv = (const float*)d_in[6];
  const float* wo = (const float*)d_in[7];
  const float* bo = (const float*)d_in[8];

  char* ws = (char*)d_ws;
  const size_t MB = 1u << 20;
  u16* Qg    = (u16*)(ws + 0 * MB);    // 8 MB [B,S,D] bf16, pre-scaled
  u16* Kg    = (u16*)(ws + 8 * MB);    // 8 MB [B,S,D]
  u16* Vt    = (u16*)(ws + 16 * MB);   // 9 MB [B,H,DH,VTS] (padded stride)
  u16* Ab    = (u16*)(ws + 25 * MB);   // 8 MB [B,S,D] attention output
  u16* xb    = (u16*)(ws + 33 * MB);   // 8 MB [B*S,D]
  u16* wqkvt = (u16*)(ws + 41 * MB);   // 6 MB [3072][1024] transposed bf16
  u16* wot   = (u16*)(ws + 47 * MB);   // 2 MB [1024][1024] transposed bf16

  k_prep<<<5120, 256, 0, stream>>>(x, wq, wk, wv, wo, xb, wqkvt, wot);
  k_gemm_qkv<<<768, 256, 0, stream>>>(xb, wqkvt, bq, bk, bv, Qg, Kg, Vt);
  k_attn<<<dim3(32, 32), 256, 0, stream>>>(Qg, Kg, Vt, Ab);
  k_gemm_out<<<512, 256, 0, stream>>>(Ab, wot, bo, (float*)d_out);
}

// Round 9
// 168.066 us; speedup vs baseline: 1.3335x; 1.0181x over previous
//
#include <hip/hip_runtime.h>

#define B_ 2
#define S_ 2048
#define D_ 1024
#define H_ 16
#define DH_ 64
#define WIN_ 256
#define VTS 2080   // Vt row stride (elements): 4KB+64B breaks L1 set-aliasing

typedef __attribute__((ext_vector_type(8))) short bf16x8;
typedef __attribute__((ext_vector_type(4))) float f32x4;
typedef unsigned short u16;

#define MFMA(a, b, c) __builtin_amdgcn_mfma_f32_16x16x32_bf16((a), (b), (c), 0, 0, 0)

__device__ __forceinline__ u16 f2b(float f) {
  unsigned int u = __float_as_uint(f);
  u += 0x7fffu + ((u >> 16) & 1u);
  return (u16)(u >> 16);
}

__device__ __forceinline__ float b2f(u16 b) {
  return __uint_as_float(((unsigned int)b) << 16);
}

__device__ __forceinline__ void async_cp16(const void* g, void* l) {
  __builtin_amdgcn_global_load_lds(
      (const __attribute__((address_space(1))) void*)g,
      (__attribute__((address_space(3))) void*)l, 16, 0, 0);
}

// ------- prep: x fp32->bf16 convert (blocks 0..4095) + weight transpose -------
__global__ void k_prep(const float* __restrict__ x,
                       const float* __restrict__ wq, const float* __restrict__ wk,
                       const float* __restrict__ wv, const float* __restrict__ wo,
                       u16* __restrict__ xb, u16* __restrict__ wqkvt, u16* __restrict__ wot) {
  __shared__ float tile[64][65];
  const int bx = blockIdx.x;
  const int t = threadIdx.x;
  if (bx < 4096) {
    int i = (bx * 256 + t) * 4;
    float4 v = *(const float4*)(x + i);
    ushort4 o;
    o.x = f2b(v.x); o.y = f2b(v.y); o.z = f2b(v.z); o.w = f2b(v.w);
    *(ushort4*)(xb + i) = o;
    return;
  }
  const int tb = bx - 4096;
  const int z = tb >> 8, rest = tb & 255;
  const float* W = z == 0 ? wq : z == 1 ? wk : z == 2 ? wv : wo;
  u16* T = z < 3 ? wqkvt + (size_t)z * 1024 * 1024 : wot;
  const int bn = (rest & 15) * 64;   // col block of W = row block of T
  const int bk = (rest >> 4) * 64;   // row block of W
  const int r = t >> 4;
  const int c = (t & 15) * 4;
#pragma unroll
  for (int i = 0; i < 4; i++) {
    float4 v = *(const float4*)(W + (size_t)(bk + r + i * 16) * D_ + bn + c);
    tile[c + 0][r + i * 16] = v.x;
    tile[c + 1][r + i * 16] = v.y;
    tile[c + 2][r + i * 16] = v.z;
    tile[c + 3][r + i * 16] = v.w;
  }
  __syncthreads();
  const int n = t >> 2, seg = (t & 3) * 16;
  __align__(16) u16 tmp[16];
#pragma unroll
  for (int u = 0; u < 16; u++) tmp[u] = f2b(tile[n][seg + u]);
  uint4* dst = (uint4*)(T + (size_t)(bn + n) * D_ + bk + seg);
  dst[0] = ((uint4*)tmp)[0];
  dst[1] = ((uint4*)tmp)[1];
}

// ---------------- 128x128 GEMM core, BK=64, XOR bank swizzle ----------------
__device__ __forceinline__ void gemm_core128(const u16* __restrict__ Ag, const u16* __restrict__ Btg,
                                             u16* As, u16* Bs, f32x4 (&acc)[4][4],
                                             int m0, int n0) {
  const int tid = threadIdx.x;
  const int w = tid >> 6, lane = tid & 63;
  const int quad = lane >> 4, l15 = lane & 15;
  const int wm = (w & 1) * 64, wn = (w >> 1) * 64;
  const int rowa = tid >> 3;                       // 0..31
  const int colsw = (((tid & 7) ^ (rowa & 7)) * 8);
  const u16* ap = Ag + (size_t)(m0 + rowa) * D_ + colsw;
  const u16* bp = Btg + (size_t)(n0 + rowa) * D_ + colsw;
  u16* As0 = As + w * 512;
  u16* Bs0 = Bs + w * 512;
  const int c0 = ((quad * 8) ^ ((l15 & 7) * 8));
  for (int kb = 0; kb < D_; kb += 64) {
#pragma unroll
    for (int i = 0; i < 4; i++) {
      async_cp16(ap + kb + (size_t)(i * 32) * D_, As0 + i * 2048);
      async_cp16(bp + kb + (size_t)(i * 32) * D_, Bs0 + i * 2048);
    }
    __syncthreads();
#pragma unroll
    for (int kh = 0; kh < 2; kh++) {
      const int c = c0 ^ (kh * 32);
      bf16x8 af[4], bfr[4];
#pragma unroll
      for (int i = 0; i < 4; i++) af[i] = *(const bf16x8*)&As[(wm + i * 16 + l15) * 64 + c];
#pragma unroll
      for (int j = 0; j < 4; j++) bfr[j] = *(const bf16x8*)&Bs[(wn + j * 16 + l15) * 64 + c];
#pragma unroll
      for (int i = 0; i < 4; i++)
#pragma unroll
        for (int j = 0; j < 4; j++) acc[i][j] = MFMA(af[i], bfr[j], acc[i][j]);
    }
    __syncthreads();
  }
}

// -------- fused QKV GEMM over N=3072; Q,K -> [B,S,D]; V -> [B,H,DH,VTS] --------
__global__ __launch_bounds__(256, 3) void k_gemm_qkv(
    const u16* __restrict__ xb, const u16* __restrict__ wqkvt,
    const float* __restrict__ bq, const float* __restrict__ bk_, const float* __restrict__ bv,
    u16* __restrict__ Qg, u16* __restrict__ Kg, u16* __restrict__ Vt) {
  __shared__ __align__(16) u16 smem[17408];   // stage: 2x8192; epilogue: 128x136
  u16* As = smem;
  u16* Bs = smem + 8192;
  const int L = blockIdx.x;
  const int xcd = L & 7, slot = L >> 3;            // slot 0..95
  const int mblk = (xcd >> 1) * 8 + (slot & 7);    // 0..31
  const int nblk = (xcd & 1) * 12 + (slot >> 3);   // 0..23
  const int n0 = nblk * 128, m0 = mblk * 128;
  const int z = n0 >> 10;
  const float* bias = z == 0 ? bq : z == 1 ? bk_ : bv;
  f32x4 acc[4][4] = {};
  gemm_core128(xb, wqkvt, As, Bs, acc, m0, n0);

  const int tid = threadIdx.x;
  const int w = tid >> 6, lane = tid & 63;
  const int quad = lane >> 4, l15 = lane & 15;
  const int wm = (w & 1) * 64, wn = (w >> 1) * 64;
  const int nloc = n0 & 1023;
  float biasv[4];
#pragma unroll
  for (int j = 0; j < 4; j++) biasv[j] = bias[nloc + wn + j * 16 + l15];
  const int b_ = m0 >> 11, sb = m0 & 2047;
  // Q pre-scale folds 1/sqrt(DH) and log2(e) so attention uses raw exp2.
  const float scale = z == 0 ? 0.125f * 1.44269504f : 1.0f;
  const int row = tid >> 4, ch = tid & 15;

  if (z < 2) {
    // C-layout -> LDS (padded stride 136) -> coalesced row-major store
#pragma unroll
    for (int j = 0; j < 4; j++)
#pragma unroll
      for (int i = 0; i < 4; i++)
#pragma unroll
        for (int r = 0; r < 4; r++)
          smem[(wm + i * 16 + quad * 4 + r) * 136 + wn + j * 16 + l15] =
              f2b((acc[i][j][r] + biasv[j]) * scale);
    __syncthreads();
    u16* OG = z == 0 ? Qg : Kg;
#pragma unroll
    for (int it = 0; it < 8; it++) {
      int rr = row + it * 16;
      bf16x8 v = *(const bf16x8*)&smem[rr * 136 + ch * 8];
      *(bf16x8*)(OG + (size_t)(m0 + rr) * D_ + nloc + ch * 8) = v;
    }
  } else {
    // write transposed into LDS: Ct[n_local][m_local]
#pragma unroll
    for (int j = 0; j < 4; j++)
#pragma unroll
      for (int i = 0; i < 4; i++)
#pragma unroll
        for (int r = 0; r < 4; r++)
          smem[(wn + j * 16 + l15) * 136 + wm + i * 16 + quad * 4 + r] =
              f2b(acc[i][j][r] + biasv[j]);
    __syncthreads();
#pragma unroll
    for (int it = 0; it < 8; it++) {
      int nn = nloc + row + it * 16;
      int h = nn >> 6, dh = nn & 63;
      bf16x8 v = *(const bf16x8*)&smem[(row + it * 16) * 136 + ch * 8];
      *(bf16x8*)(Vt + ((size_t)(b_ * H_ + h) * DH_ + dh) * VTS + sb + ch * 8) = v;
    }
  }
}

// ---------- output projection: 64x128 tiles, BK=128 (32 MFMA/barrier) ----------
// R9: same tile/grid/occupancy as R8, but K-block 64->128: 8 barrier-pairs
// instead of 16, qkv-equal MFMA density. LDS 48KB (A 16K + B 32K), 2 blk/CU.
__global__ __launch_bounds__(256, 2) void k_gemm_out(
    const u16* __restrict__ Ab, const u16* __restrict__ wot,
    const float* __restrict__ bo, float* __restrict__ out) {
  __shared__ __align__(16) u16 smem[24576];   // A 64x128 + B 128x128; epilogue 64x136
  u16* As = smem;
  u16* Bs = smem + 8192;
  const int L = blockIdx.x;
  const int xcd = L & 7, slot = L >> 3;        // slot 0..63
  const int mblk = xcd * 8 + (slot & 7);       // 0..63
  const int nblk = slot >> 3;                  // 0..7
  const int n0 = nblk * 128, m0 = mblk * 64;
  const int tid = threadIdx.x;
  const int w = tid >> 6, lane = tid & 63;
  const int quad = lane >> 4, l15 = lane & 15;
  const int wn = w * 32;
  // staging: 16 granules (16B) per 256B row; slot g holds global granule g^(row&15)
  const int rowa = tid >> 4;                   // 0..15
  const int gg = (tid & 15) ^ rowa;
  const u16* ap = Ab + (size_t)(m0 + rowa) * D_ + gg * 8;
  const u16* bp = wot + (size_t)(n0 + rowa) * D_ + gg * 8;
  u16* As0 = As + w * 512;
  u16* Bs0 = Bs + w * 512;
  f32x4 acc[4][2] = {};
  for (int kb = 0; kb < D_; kb += 128) {
#pragma unroll
    for (int i = 0; i < 4; i++)
      async_cp16(ap + kb + (size_t)(i * 16) * D_, As0 + i * 2048);
#pragma unroll
    for (int i = 0; i < 8; i++)
      async_cp16(bp + kb + (size_t)(i * 16) * D_, Bs0 + i * 2048);
    __syncthreads();
#pragma unroll
    for (int kh = 0; kh < 4; kh++) {
      const int cs = (((quad + 4 * kh) ^ l15) * 8);
      bf16x8 af[4], bfr[2];
#pragma unroll
      for (int i = 0; i < 4; i++) af[i] = *(const bf16x8*)&As[(i * 16 + l15) * 128 + cs];
#pragma unroll
      for (int j = 0; j < 2; j++) bfr[j] = *(const bf16x8*)&Bs[(wn + j * 16 + l15) * 128 + cs];
#pragma unroll
      for (int i = 0; i < 4; i++)
#pragma unroll
        for (int j = 0; j < 2; j++) acc[i][j] = MFMA(af[i], bfr[j], acc[i][j]);
    }
    __syncthreads();
  }
  float biasv[2];
#pragma unroll
  for (int j = 0; j < 2; j++) biasv[j] = bo[n0 + wn + j * 16 + l15];
#pragma unroll
  for (int j = 0; j < 2; j++)
#pragma unroll
    for (int i = 0; i < 4; i++)
#pragma unroll
      for (int r = 0; r < 4; r++)
        smem[(i * 16 + quad * 4 + r) * 136 + wn + j * 16 + l15] = f2b(acc[i][j][r] + biasv[j]);
  __syncthreads();
  const int row = tid >> 4, ch = tid & 15;
#pragma unroll
  for (int it = 0; it < 4; it++) {
    int rr = row + it * 16;
    bf16x8 v = *(const bf16x8*)&smem[rr * 136 + ch * 8];
    float4 f0, f1;
    f0.x = b2f((u16)v[0]); f0.y = b2f((u16)v[1]); f0.z = b2f((u16)v[2]); f0.w = b2f((u16)v[3]);
    f1.x = b2f((u16)v[4]); f1.y = b2f((u16)v[5]); f1.z = b2f((u16)v[6]); f1.w = b2f((u16)v[7]);
    float* dst = out + (size_t)(m0 + rr) * D_ + n0 + ch * 8;
    *(float4*)dst = f0;
    *(float4*)(dst + 4) = f1;
  }
}

// ---------------- windowed flash attention, static softmax ----------------
// Q,K in [B,S,D] (Q pre-scaled by 0.125*log2e); Vt in [B,H,DH,VTS]; out Ab [B,S,D].
__global__ __launch_bounds__(256, 4) void k_attn(
    const u16* __restrict__ Qg, const u16* __restrict__ Kg,
    const u16* __restrict__ Vt, u16* __restrict__ Ab) {
  __shared__ __align__(16) u16 Plds[4][2][16 * 72];
  const int tid = threadIdx.x;
  const int w = tid >> 6, lane = tid & 63;
  const int quad = lane >> 4, l15 = lane & 15;
  const int bh = blockIdx.x;
  const int qw = blockIdx.y * 64 + w * 16;
  const int b_ = bh >> 4, h = bh & 15;

  const u16* Qbase = Qg + (size_t)(b_ * S_ + qw + l15) * D_ + h * DH_ + quad * 8;
  bf16x8 aq0 = *(const bf16x8*)Qbase;
  bf16x8 aq1 = *(const bf16x8*)(Qbase + 32);

  float lr[4] = {0.f, 0.f, 0.f, 0.f};
  f32x4 Oacc[4] = {};

  const u16* Kb = Kg + (size_t)b_ * S_ * D_ + h * DH_;
  const u16* Vb = Vt + (size_t)bh * DH_ * VTS;
  const int klo = qw >= WIN_ ? ((qw - WIN_) & ~31) : 0;
  u16* Pb[2] = {&Plds[w][0][0], &Plds[w][1][0]};
  int par = 0;

  for (int k0 = klo; k0 < qw + 16; k0 += 32) {
    // --- issue ALL global loads first (K for QK^T, V for PV) ---
    const u16* Kt0 = Kb + (size_t)(k0 + l15) * D_ + quad * 8;
    bf16x8 b00 = *(const bf16x8*)Kt0;
    bf16x8 b01 = *(const bf16x8*)(Kt0 + 32);
    bf16x8 b10 = *(const bf16x8*)(Kt0 + (size_t)16 * D_);
    bf16x8 b11 = *(const bf16x8*)(Kt0 + (size_t)16 * D_ + 32);
    const u16* Vt0 = Vb + (size_t)l15 * VTS + k0 + quad * 8;
    bf16x8 v0 = *(const bf16x8*)(Vt0);
    bf16x8 v1 = *(const bf16x8*)(Vt0 + (size_t)16 * VTS);
    bf16x8 v2 = *(const bf16x8*)(Vt0 + (size_t)32 * VTS);
    bf16x8 v3 = *(const bf16x8*)(Vt0 + (size_t)48 * VTS);

    f32x4 s0 = {0.f, 0.f, 0.f, 0.f}, s1 = {0.f, 0.f, 0.f, 0.f};
    s0 = MFMA(aq0, b00, s0);
    s0 = MFMA(aq1, b01, s0);
    s1 = MFMA(aq0, b10, s1);
    s1 = MFMA(aq1, b11, s1);

    const int key0 = k0 + l15, key1 = k0 + 16 + l15;
#pragma unroll
    for (int r = 0; r < 4; r++) {
      int q = qw + quad * 4 + r;
      float p0 = (key0 <= q && key0 + WIN_ >= q) ? __builtin_amdgcn_exp2f(s0[r]) : 0.f;
      float p1 = (key1 <= q && key1 + WIN_ >= q) ? __builtin_amdgcn_exp2f(s1[r]) : 0.f;
      s0[r] = p0; s1[r] = p1;
      lr[r] += p0 + p1;
    }
    // C-layout -> LDS -> A-layout (wave-private, double-buffered: no pre-drain)
    u16* P = Pb[par];
#pragma unroll
    for (int r = 0; r < 4; r++) {
      P[(quad * 4 + r) * 72 + l15] = f2b(s0[r]);
      P[(quad * 4 + r) * 72 + 16 + l15] = f2b(s1[r]);
    }
    asm volatile("s_waitcnt lgkmcnt(0)" ::: "memory");
    bf16x8 apf = *(const bf16x8*)&P[l15 * 72 + quad * 8];
    Oacc[0] = MFMA(apf, v0, Oacc[0]);
    Oacc[1] = MFMA(apf, v1, Oacc[1]);
    Oacc[2] = MFMA(apf, v2, Oacc[2]);
    Oacc[3] = MFMA(apf, v3, Oacc[3]);
    par ^= 1;
  }

#pragma unroll
  for (int off = 1; off < 16; off <<= 1)
#pragma unroll
    for (int r = 0; r < 4; r++) lr[r] += __shfl_xor(lr[r], off);
  float inv[4];
#pragma unroll
  for (int r = 0; r < 4; r++) inv[r] = 1.0f / lr[r];

  // O: C-layout -> wave LDS -> two coalesced bf16x8 stores per lane (full 16x64)
  asm volatile("s_waitcnt lgkmcnt(0)" ::: "memory");
  u16* P = Pb[0];
#pragma unroll
  for (int j = 0; j < 4; j++)
#pragma unroll
    for (int r = 0; r < 4; r++)
      P[(quad * 4 + r) * 72 + j * 16 + l15] = f2b(Oacc[j][r] * inv[r]);
  asm volatile("s_waitcnt lgkmcnt(0)" ::: "memory");
  {
    int rq = lane >> 2, cc = lane & 3;
    bf16x8 v0 = *(const bf16x8*)&P[rq * 72 + cc * 16];
    bf16x8 v1 = *(const bf16x8*)&P[rq * 72 + cc * 16 + 8];
    u16* dst = Ab + (size_t)(b_ * S_ + qw + rq) * D_ + h * DH_ + cc * 16;
    *(bf16x8*)dst = v0;
    *(bf16x8*)(dst + 8) = v1;
  }
}

extern "C" void kernel_launch(void* const* d_in, const int* in_sizes, int n_in,
                              void* d_out, int out_size, void* d_ws, size_t ws_size,
                              hipStream_t stream) {
  const float* x  = (const float*)d_in[0];
  const float* wq = (const float*)d_in[1];
  const float* bq = (const float*)d_in[2];
  const float* wk = (const float*)d_in[3];
  const float* bk = (const float*)d_in[4];
  const float* wv = (const float*)d_in[5];
  const float* bv = (const float*)d_in[6];
  const float* wo = (const float*)d_in[7];
  const float* bo = (const float*)d_in[8];

  char* ws = (char*)d_ws;
  const size_t MB = 1u << 20;
  u16* Qg    = (u16*)(ws + 0 * MB);    // 8 MB [B,S,D] bf16, pre-scaled
  u16* Kg    = (u16*)(ws + 8 * MB);    // 8 MB [B,S,D]
  u16* Vt    = (u16*)(ws + 16 * MB);   // 9 MB [B,H,DH,VTS] (padded stride)
  u16* Ab    = (u16*)(ws + 25 * MB);   // 8 MB [B,S,D] attention output
  u16* xb    = (u16*)(ws + 33 * MB);   // 8 MB [B*S,D]
  u16* wqkvt = (u16*)(ws + 41 * MB);   // 6 MB [3072][1024] transposed bf16
  u16* wot   = (u16*)(ws + 47 * MB);   // 2 MB [1024][1024] transposed bf16

  k_prep<<<5120, 256, 0, stream>>>(x, wq, wk, wv, wo, xb, wqkvt, wot);
  k_gemm_qkv<<<768, 256, 0, stream>>>(xb, wqkvt, bq, bk, bv, Qg, Kg, Vt);
  k_attn<<<dim3(32, 32), 256, 0, stream>>>(Qg, Kg, Vt, Ab);
  k_gemm_out<<<512, 256, 0, stream>>>(Ab, wot, bo, (float*)d_out);
}

// Round 10
// 165.283 us; speedup vs baseline: 1.3559x; 1.0168x over previous
//
#include <hip/hip_runtime.h>

#define B_ 2
#define S_ 2048
#define D_ 1024
#define H_ 16
#define DH_ 64
#define WIN_ 256
#define VTS 2080   // Vt row stride (elements): 4KB+64B breaks L1 set-aliasing

typedef __attribute__((ext_vector_type(8))) short bf16x8;
typedef __attribute__((ext_vector_type(4))) float f32x4;
typedef unsigned short u16;

#define MFMA(a, b, c) __builtin_amdgcn_mfma_f32_16x16x32_bf16((a), (b), (c), 0, 0, 0)

__device__ __forceinline__ u16 f2b(float f) {
  unsigned int u = __float_as_uint(f);
  u += 0x7fffu + ((u >> 16) & 1u);
  return (u16)(u >> 16);
}

__device__ __forceinline__ float b2f(u16 b) {
  return __uint_as_float(((unsigned int)b) << 16);
}

__device__ __forceinline__ void async_cp16(const void* g, void* l) {
  __builtin_amdgcn_global_load_lds(
      (const __attribute__((address_space(1))) void*)g,
      (__attribute__((address_space(3))) void*)l, 16, 0, 0);
}

// ------- prep: x fp32->bf16 convert (blocks 0..4095) + weight transpose -------
__global__ void k_prep(const float* __restrict__ x,
                       const float* __restrict__ wq, const float* __restrict__ wk,
                       const float* __restrict__ wv, const float* __restrict__ wo,
                       u16* __restrict__ xb, u16* __restrict__ wqkvt, u16* __restrict__ wot) {
  __shared__ float tile[64][65];
  const int bx = blockIdx.x;
  const int t = threadIdx.x;
  if (bx < 4096) {
    int i = (bx * 256 + t) * 4;
    float4 v = *(const float4*)(x + i);
    ushort4 o;
    o.x = f2b(v.x); o.y = f2b(v.y); o.z = f2b(v.z); o.w = f2b(v.w);
    *(ushort4*)(xb + i) = o;
    return;
  }
  const int tb = bx - 4096;
  const int z = tb >> 8, rest = tb & 255;
  const float* W = z == 0 ? wq : z == 1 ? wk : z == 2 ? wv : wo;
  u16* T = z < 3 ? wqkvt + (size_t)z * 1024 * 1024 : wot;
  const int bn = (rest & 15) * 64;   // col block of W = row block of T
  const int bk = (rest >> 4) * 64;   // row block of W
  const int r = t >> 4;
  const int c = (t & 15) * 4;
#pragma unroll
  for (int i = 0; i < 4; i++) {
    float4 v = *(const float4*)(W + (size_t)(bk + r + i * 16) * D_ + bn + c);
    tile[c + 0][r + i * 16] = v.x;
    tile[c + 1][r + i * 16] = v.y;
    tile[c + 2][r + i * 16] = v.z;
    tile[c + 3][r + i * 16] = v.w;
  }
  __syncthreads();
  const int n = t >> 2, seg = (t & 3) * 16;
  __align__(16) u16 tmp[16];
#pragma unroll
  for (int u = 0; u < 16; u++) tmp[u] = f2b(tile[n][seg + u]);
  uint4* dst = (uint4*)(T + (size_t)(bn + n) * D_ + bk + seg);
  dst[0] = ((uint4*)tmp)[0];
  dst[1] = ((uint4*)tmp)[1];
}

// ---------------- 128x128 GEMM core, BK=64, XOR bank swizzle ----------------
__device__ __forceinline__ void gemm_core128(const u16* __restrict__ Ag, const u16* __restrict__ Btg,
                                             u16* As, u16* Bs, f32x4 (&acc)[4][4],
                                             int m0, int n0) {
  const int tid = threadIdx.x;
  const int w = tid >> 6, lane = tid & 63;
  const int quad = lane >> 4, l15 = lane & 15;
  const int wm = (w & 1) * 64, wn = (w >> 1) * 64;
  const int rowa = tid >> 3;                       // 0..31
  const int colsw = (((tid & 7) ^ (rowa & 7)) * 8);
  const u16* ap = Ag + (size_t)(m0 + rowa) * D_ + colsw;
  const u16* bp = Btg + (size_t)(n0 + rowa) * D_ + colsw;
  u16* As0 = As + w * 512;
  u16* Bs0 = Bs + w * 512;
  const int c0 = ((quad * 8) ^ ((l15 & 7) * 8));
  for (int kb = 0; kb < D_; kb += 64) {
#pragma unroll
    for (int i = 0; i < 4; i++) {
      async_cp16(ap + kb + (size_t)(i * 32) * D_, As0 + i * 2048);
      async_cp16(bp + kb + (size_t)(i * 32) * D_, Bs0 + i * 2048);
    }
    __syncthreads();
#pragma unroll
    for (int kh = 0; kh < 2; kh++) {
      const int c = c0 ^ (kh * 32);
      bf16x8 af[4], bfr[4];
#pragma unroll
      for (int i = 0; i < 4; i++) af[i] = *(const bf16x8*)&As[(wm + i * 16 + l15) * 64 + c];
#pragma unroll
      for (int j = 0; j < 4; j++) bfr[j] = *(const bf16x8*)&Bs[(wn + j * 16 + l15) * 64 + c];
#pragma unroll
      for (int i = 0; i < 4; i++)
#pragma unroll
        for (int j = 0; j < 4; j++) acc[i][j] = MFMA(af[i], bfr[j], acc[i][j]);
    }
    __syncthreads();
  }
}

// -------- fused QKV GEMM over N=3072; Q,K -> [B,S,D]; V -> [B,H,DH,VTS] --------
__global__ __launch_bounds__(256, 3) void k_gemm_qkv(
    const u16* __restrict__ xb, const u16* __restrict__ wqkvt,
    const float* __restrict__ bq, const float* __restrict__ bk_, const float* __restrict__ bv,
    u16* __restrict__ Qg, u16* __restrict__ Kg, u16* __restrict__ Vt) {
  __shared__ __align__(16) u16 smem[17408];   // stage: 2x8192; epilogue: 128x136
  u16* As = smem;
  u16* Bs = smem + 8192;
  const int L = blockIdx.x;
  const int xcd = L & 7, slot = L >> 3;            // slot 0..95
  const int mblk = (xcd >> 1) * 8 + (slot & 7);    // 0..31
  const int nblk = (xcd & 1) * 12 + (slot >> 3);   // 0..23
  const int n0 = nblk * 128, m0 = mblk * 128;
  const int z = n0 >> 10;
  const float* bias = z == 0 ? bq : z == 1 ? bk_ : bv;
  f32x4 acc[4][4] = {};
  gemm_core128(xb, wqkvt, As, Bs, acc, m0, n0);

  const int tid = threadIdx.x;
  const int w = tid >> 6, lane = tid & 63;
  const int quad = lane >> 4, l15 = lane & 15;
  const int wm = (w & 1) * 64, wn = (w >> 1) * 64;
  const int nloc = n0 & 1023;
  float biasv[4];
#pragma unroll
  for (int j = 0; j < 4; j++) biasv[j] = bias[nloc + wn + j * 16 + l15];
  const int b_ = m0 >> 11, sb = m0 & 2047;
  // Q pre-scale folds 1/sqrt(DH) and log2(e) so attention uses raw exp2.
  const float scale = z == 0 ? 0.125f * 1.44269504f : 1.0f;
  const int row = tid >> 4, ch = tid & 15;

  if (z < 2) {
    // C-layout -> LDS (padded stride 136) -> coalesced row-major store
#pragma unroll
    for (int j = 0; j < 4; j++)
#pragma unroll
      for (int i = 0; i < 4; i++)
#pragma unroll
        for (int r = 0; r < 4; r++)
          smem[(wm + i * 16 + quad * 4 + r) * 136 + wn + j * 16 + l15] =
              f2b((acc[i][j][r] + biasv[j]) * scale);
    __syncthreads();
    u16* OG = z == 0 ? Qg : Kg;
#pragma unroll
    for (int it = 0; it < 8; it++) {
      int rr = row + it * 16;
      bf16x8 v = *(const bf16x8*)&smem[rr * 136 + ch * 8];
      *(bf16x8*)(OG + (size_t)(m0 + rr) * D_ + nloc + ch * 8) = v;
    }
  } else {
    // write transposed into LDS: Ct[n_local][m_local]
#pragma unroll
    for (int j = 0; j < 4; j++)
#pragma unroll
      for (int i = 0; i < 4; i++)
#pragma unroll
        for (int r = 0; r < 4; r++)
          smem[(wn + j * 16 + l15) * 136 + wm + i * 16 + quad * 4 + r] =
              f2b(acc[i][j][r] + biasv[j]);
    __syncthreads();
#pragma unroll
    for (int it = 0; it < 8; it++) {
      int nn = nloc + row + it * 16;
      int h = nn >> 6, dh = nn & 63;
      bf16x8 v = *(const bf16x8*)&smem[(row + it * 16) * 136 + ch * 8];
      *(bf16x8*)(Vt + ((size_t)(b_ * H_ + h) * DH_ + dh) * VTS + sb + ch * 8) = v;
    }
  }
}

// ---------- output projection: 64x128 tiles, BK=128 (32 MFMA/barrier) ----------
__global__ __launch_bounds__(256, 2) void k_gemm_out(
    const u16* __restrict__ Ab, const u16* __restrict__ wot,
    const float* __restrict__ bo, float* __restrict__ out) {
  __shared__ __align__(16) u16 smem[24576];   // A 64x128 + B 128x128; epilogue 64x136
  u16* As = smem;
  u16* Bs = smem + 8192;
  const int L = blockIdx.x;
  const int xcd = L & 7, slot = L >> 3;        // slot 0..63
  const int mblk = xcd * 8 + (slot & 7);       // 0..63
  const int nblk = slot >> 3;                  // 0..7
  const int n0 = nblk * 128, m0 = mblk * 64;
  const int tid = threadIdx.x;
  const int w = tid >> 6, lane = tid & 63;
  const int quad = lane >> 4, l15 = lane & 15;
  const int wn = w * 32;
  const int rowa = tid >> 4;                   // 0..15
  const int gg = (tid & 15) ^ rowa;
  const u16* ap = Ab + (size_t)(m0 + rowa) * D_ + gg * 8;
  const u16* bp = wot + (size_t)(n0 + rowa) * D_ + gg * 8;
  u16* As0 = As + w * 512;
  u16* Bs0 = Bs + w * 512;
  f32x4 acc[4][2] = {};
  for (int kb = 0; kb < D_; kb += 128) {
#pragma unroll
    for (int i = 0; i < 4; i++)
      async_cp16(ap + kb + (size_t)(i * 16) * D_, As0 + i * 2048);
#pragma unroll
    for (int i = 0; i < 8; i++)
      async_cp16(bp + kb + (size_t)(i * 16) * D_, Bs0 + i * 2048);
    __syncthreads();
#pragma unroll
    for (int kh = 0; kh < 4; kh++) {
      const int cs = (((quad + 4 * kh) ^ l15) * 8);
      bf16x8 af[4], bfr[2];
#pragma unroll
      for (int i = 0; i < 4; i++) af[i] = *(const bf16x8*)&As[(i * 16 + l15) * 128 + cs];
#pragma unroll
      for (int j = 0; j < 2; j++) bfr[j] = *(const bf16x8*)&Bs[(wn + j * 16 + l15) * 128 + cs];
#pragma unroll
      for (int i = 0; i < 4; i++)
#pragma unroll
        for (int j = 0; j < 2; j++) acc[i][j] = MFMA(af[i], bfr[j], acc[i][j]);
    }
    __syncthreads();
  }
  float biasv[2];
#pragma unroll
  for (int j = 0; j < 2; j++) biasv[j] = bo[n0 + wn + j * 16 + l15];
#pragma unroll
  for (int j = 0; j < 2; j++)
#pragma unroll
    for (int i = 0; i < 4; i++)
#pragma unroll
      for (int r = 0; r < 4; r++)
        smem[(i * 16 + quad * 4 + r) * 136 + wn + j * 16 + l15] = f2b(acc[i][j][r] + biasv[j]);
  __syncthreads();
  const int row = tid >> 4, ch = tid & 15;
#pragma unroll
  for (int it = 0; it < 4; it++) {
    int rr = row + it * 16;
    bf16x8 v = *(const bf16x8*)&smem[rr * 136 + ch * 8];
    float4 f0, f1;
    f0.x = b2f((u16)v[0]); f0.y = b2f((u16)v[1]); f0.z = b2f((u16)v[2]); f0.w = b2f((u16)v[3]);
    f1.x = b2f((u16)v[4]); f1.y = b2f((u16)v[5]); f1.z = b2f((u16)v[6]); f1.w = b2f((u16)v[7]);
    float* dst = out + (size_t)(m0 + rr) * D_ + n0 + ch * 8;
    *(float4*)dst = f0;
    *(float4*)(dst + 4) = f1;
  }
}

// ---------------- windowed flash attention, transposed-MFMA scheme ----------------
// R10: S^T = MFMA(K_frag, Q_frag) puts queries in lanes; P^T B-fragment built
// in-register via 8 __shfl + 4 selects — NO LDS round-trip, no lgkm drains,
// no asm barriers (compiler free to pipeline K/V loads across tiles).
// O^T = MFMA(V_frag, P^T) accumulates with lane=query. LDS used once (epilogue).
__global__ __launch_bounds__(256, 4) void k_attn(
    const u16* __restrict__ Qg, const u16* __restrict__ Kg,
    const u16* __restrict__ Vt, u16* __restrict__ Ab) {
  __shared__ __align__(16) u16 Plds[4][16 * 72];
  const int tid = threadIdx.x;
  const int w = tid >> 6, lane = tid & 63;
  const int quad = lane >> 4, l15 = lane & 15;
  const int bh = blockIdx.x;
  const int qw = blockIdx.y * 64 + w * 16;
  const int b_ = bh >> 4, h = bh & 15;

  // Q fragment: lane = query, quad*8 dh chunk (pre-scaled by 0.125*log2e)
  const u16* Qbase = Qg + (size_t)(b_ * S_ + qw + l15) * D_ + h * DH_ + quad * 8;
  bf16x8 aq0 = *(const bf16x8*)Qbase;
  bf16x8 aq1 = *(const bf16x8*)(Qbase + 32);

  float lr = 0.f;
  f32x4 Oacc[4] = {};

  const u16* Kb = Kg + (size_t)b_ * S_ * D_ + h * DH_;
  const u16* Vb = Vt + (size_t)bh * DH_ * VTS;
  const int klo = qw >= WIN_ ? ((qw - WIN_) & ~31) : 0;
  const int q = qw + l15;
  const int srcA = l15 + ((quad & 1) ? 32 : 0);
  const int srcB = srcA + 16;

  for (int k0 = klo; k0 < qw + 16; k0 += 32) {
    // K fragment as A-operand: lane = key row
    const u16* Kt0 = Kb + (size_t)(k0 + l15) * D_ + quad * 8;
    bf16x8 k00 = *(const bf16x8*)Kt0;
    bf16x8 k01 = *(const bf16x8*)(Kt0 + 32);
    bf16x8 k10 = *(const bf16x8*)(Kt0 + (size_t)16 * D_);
    bf16x8 k11 = *(const bf16x8*)(Kt0 + (size_t)16 * D_ + 32);
    const u16* Vt0 = Vb + (size_t)l15 * VTS + k0 + quad * 8;
    bf16x8 v0 = *(const bf16x8*)(Vt0);
    bf16x8 v1 = *(const bf16x8*)(Vt0 + (size_t)16 * VTS);
    bf16x8 v2 = *(const bf16x8*)(Vt0 + (size_t)32 * VTS);
    bf16x8 v3 = *(const bf16x8*)(Vt0 + (size_t)48 * VTS);

    // S^T: col=lane=query, row=quad*4+r=key-offset
    f32x4 s0 = {0.f, 0.f, 0.f, 0.f}, s1 = {0.f, 0.f, 0.f, 0.f};
    s0 = MFMA(k00, aq0, s0);
    s0 = MFMA(k01, aq1, s0);
    s1 = MFMA(k10, aq0, s1);
    s1 = MFMA(k11, aq1, s1);

    float e[8];
#pragma unroll
    for (int r = 0; r < 4; r++) {
      int key0 = k0 + quad * 4 + r;
      int key1 = key0 + 16;
      float p0 = (key0 <= q && key0 + WIN_ >= q) ? __builtin_amdgcn_exp2f(s0[r]) : 0.f;
      float p1 = (key1 <= q && key1 + WIN_ >= q) ? __builtin_amdgcn_exp2f(s1[r]) : 0.f;
      e[r] = p0; e[4 + r] = p1;
      lr += p0 + p1;
    }
    // pack exp values to bf16 pairs, then cross-lane transpose into P^T B-frag
    unsigned int s0p01 = (unsigned)f2b(e[0]) | ((unsigned)f2b(e[1]) << 16);
    unsigned int s0p23 = (unsigned)f2b(e[2]) | ((unsigned)f2b(e[3]) << 16);
    unsigned int s1p01 = (unsigned)f2b(e[4]) | ((unsigned)f2b(e[5]) << 16);
    unsigned int s1p23 = (unsigned)f2b(e[6]) | ((unsigned)f2b(e[7]) << 16);
    unsigned int a0 = (unsigned)__shfl((int)s0p01, srcA);
    unsigned int a1 = (unsigned)__shfl((int)s0p23, srcA);
    unsigned int a2 = (unsigned)__shfl((int)s0p01, srcB);
    unsigned int a3 = (unsigned)__shfl((int)s0p23, srcB);
    unsigned int c0 = (unsigned)__shfl((int)s1p01, srcA);
    unsigned int c1 = (unsigned)__shfl((int)s1p23, srcA);
    unsigned int c2 = (unsigned)__shfl((int)s1p01, srcB);
    unsigned int c3 = (unsigned)__shfl((int)s1p23, srcB);
    union { unsigned int u[4]; bf16x8 v; } pf;
    const bool lo = quad < 2;
    pf.u[0] = lo ? a0 : c0;
    pf.u[1] = lo ? a1 : c1;
    pf.u[2] = lo ? a2 : c2;
    pf.u[3] = lo ? a3 : c3;

    // O^T += V^T · P^T : col=lane=query, row=dh-within-group
    Oacc[0] = MFMA(v0, pf.v, Oacc[0]);
    Oacc[1] = MFMA(v1, pf.v, Oacc[1]);
    Oacc[2] = MFMA(v2, pf.v, Oacc[2]);
    Oacc[3] = MFMA(v3, pf.v, Oacc[3]);
  }

  // lr per lane covers this quad's key rows; sum across quads (same l15)
  lr += __shfl_xor(lr, 16);
  lr += __shfl_xor(lr, 32);
  const float inv = 1.0f / lr;

  // epilogue: lane=query holds dh=j*16+quad*4+r -> LDS row l15 -> coalesced store
  u16* P = &Plds[w][0];
#pragma unroll
  for (int j = 0; j < 4; j++)
#pragma unroll
    for (int r = 0; r < 4; r++)
      P[l15 * 72 + j * 16 + quad * 4 + r] = f2b(Oacc[j][r] * inv);
  {
    int rq = lane >> 2, cc = lane & 3;
    bf16x8 ov0 = *(const bf16x8*)&P[rq * 72 + cc * 16];
    bf16x8 ov1 = *(const bf16x8*)&P[rq * 72 + cc * 16 + 8];
    u16* dst = Ab + (size_t)(b_ * S_ + qw + rq) * D_ + h * DH_ + cc * 16;
    *(bf16x8*)dst = ov0;
    *(bf16x8*)(dst + 8) = ov1;
  }
}

extern "C" void kernel_launch(void* const* d_in, const int* in_sizes, int n_in,
                              void* d_out, int out_size, void* d_ws, size_t ws_size,
                              hipStream_t stream) {
  const float* x  = (const float*)d_in[0];
  const float* wq = (const float*)d_in[1];
  const float* bq = (const float*)d_in[2];
  const float* wk = (const float*)d_in[3];
  const float* bk = (const float*)d_in[4];
  const float* wv = (const float*)d_in[5];
  const float* bv = (const float*)d_in[6];
  const float* wo = (const float*)d_in[7];
  const float* bo = (const float*)d_in[8];

  char* ws = (char*)d_ws;
  const size_t MB = 1u << 20;
  u16* Qg    = (u16*)(ws + 0 * MB);    // 8 MB [B,S,D] bf16, pre-scaled
  u16* Kg    = (u16*)(ws + 8 * MB);    // 8 MB [B,S,D]
  u16* Vt    = (u16*)(ws + 16 * MB);   // 9 MB [B,H,DH,VTS] (padded stride)
  u16* Ab    = (u16*)(ws + 25 * MB);   // 8 MB [B,S,D] attention output
  u16* xb    = (u16*)(ws + 33 * MB);   // 8 MB [B*S,D]
  u16* wqkvt = (u16*)(ws + 41 * MB);   // 6 MB [3072][1024] transposed bf16
  u16* wot   = (u16*)(ws + 47 * MB);   // 2 MB [1024][1024] transposed bf16

  k_prep<<<5120, 256, 0, stream>>>(x, wq, wk, wv, wo, xb, wqkvt, wot);
  k_gemm_qkv<<<768, 256, 0, stream>>>(xb, wqkvt, bq, bk, bv, Qg, Kg, Vt);
  k_attn<<<dim3(32, 32), 256, 0, stream>>>(Qg, Kg, Vt, Ab);
  k_gemm_out<<<512, 256, 0, stream>>>(Ab, wot, bo, (float*)d_out);
}

// Round 11
// 161.133 us; speedup vs baseline: 1.3909x; 1.0258x over previous
//
#include <hip/hip_runtime.h>

#define B_ 2
#define S_ 2048
#define D_ 1024
#define H_ 16
#define DH_ 64
#define WIN_ 256
#define VTS 2080   // Vt row stride (elements): 4KB+64B breaks L1 set-aliasing

typedef __attribute__((ext_vector_type(8))) short bf16x8;
typedef __attribute__((ext_vector_type(4))) float f32x4;
typedef unsigned short u16;

#define MFMA(a, b, c) __builtin_amdgcn_mfma_f32_16x16x32_bf16((a), (b), (c), 0, 0, 0)

__device__ __forceinline__ u16 f2b(float f) {
  unsigned int u = __float_as_uint(f);
  u += 0x7fffu + ((u >> 16) & 1u);
  return (u16)(u >> 16);
}

__device__ __forceinline__ float b2f(u16 b) {
  return __uint_as_float(((unsigned int)b) << 16);
}

__device__ __forceinline__ void async_cp16(const void* g, void* l) {
  __builtin_amdgcn_global_load_lds(
      (const __attribute__((address_space(1))) void*)g,
      (__attribute__((address_space(3))) void*)l, 16, 0, 0);
}

// ------- prep: x fp32->bf16 convert (blocks 0..4095) + weight transpose -------
__global__ void k_prep(const float* __restrict__ x,
                       const float* __restrict__ wq, const float* __restrict__ wk,
                       const float* __restrict__ wv, const float* __restrict__ wo,
                       u16* __restrict__ xb, u16* __restrict__ wqkvt, u16* __restrict__ wot) {
  __shared__ float tile[64][65];
  const int bx = blockIdx.x;
  const int t = threadIdx.x;
  if (bx < 4096) {
    int i = (bx * 256 + t) * 4;
    float4 v = *(const float4*)(x + i);
    ushort4 o;
    o.x = f2b(v.x); o.y = f2b(v.y); o.z = f2b(v.z); o.w = f2b(v.w);
    *(ushort4*)(xb + i) = o;
    return;
  }
  const int tb = bx - 4096;
  const int z = tb >> 8, rest = tb & 255;
  const float* W = z == 0 ? wq : z == 1 ? wk : z == 2 ? wv : wo;
  u16* T = z < 3 ? wqkvt + (size_t)z * 1024 * 1024 : wot;
  const int bn = (rest & 15) * 64;   // col block of W = row block of T
  const int bk = (rest >> 4) * 64;   // row block of W
  const int r = t >> 4;
  const int c = (t & 15) * 4;
#pragma unroll
  for (int i = 0; i < 4; i++) {
    float4 v = *(const float4*)(W + (size_t)(bk + r + i * 16) * D_ + bn + c);
    tile[c + 0][r + i * 16] = v.x;
    tile[c + 1][r + i * 16] = v.y;
    tile[c + 2][r + i * 16] = v.z;
    tile[c + 3][r + i * 16] = v.w;
  }
  __syncthreads();
  const int n = t >> 2, seg = (t & 3) * 16;
  __align__(16) u16 tmp[16];
#pragma unroll
  for (int u = 0; u < 16; u++) tmp[u] = f2b(tile[n][seg + u]);
  uint4* dst = (uint4*)(T + (size_t)(bn + n) * D_ + bk + seg);
  dst[0] = ((uint4*)tmp)[0];
  dst[1] = ((uint4*)tmp)[1];
}

// ---------------- 128x128 GEMM core, BK=64, XOR bank swizzle ----------------
__device__ __forceinline__ void gemm_core128(const u16* __restrict__ Ag, const u16* __restrict__ Btg,
                                             u16* As, u16* Bs, f32x4 (&acc)[4][4],
                                             int m0, int n0) {
  const int tid = threadIdx.x;
  const int w = tid >> 6, lane = tid & 63;
  const int quad = lane >> 4, l15 = lane & 15;
  const int wm = (w & 1) * 64, wn = (w >> 1) * 64;
  const int rowa = tid >> 3;                       // 0..31
  const int colsw = (((tid & 7) ^ (rowa & 7)) * 8);
  const u16* ap = Ag + (size_t)(m0 + rowa) * D_ + colsw;
  const u16* bp = Btg + (size_t)(n0 + rowa) * D_ + colsw;
  u16* As0 = As + w * 512;
  u16* Bs0 = Bs + w * 512;
  const int c0 = ((quad * 8) ^ ((l15 & 7) * 8));
  for (int kb = 0; kb < D_; kb += 64) {
#pragma unroll
    for (int i = 0; i < 4; i++) {
      async_cp16(ap + kb + (size_t)(i * 32) * D_, As0 + i * 2048);
      async_cp16(bp + kb + (size_t)(i * 32) * D_, Bs0 + i * 2048);
    }
    __syncthreads();
#pragma unroll
    for (int kh = 0; kh < 2; kh++) {
      const int c = c0 ^ (kh * 32);
      bf16x8 af[4], bfr[4];
#pragma unroll
      for (int i = 0; i < 4; i++) af[i] = *(const bf16x8*)&As[(wm + i * 16 + l15) * 64 + c];
#pragma unroll
      for (int j = 0; j < 4; j++) bfr[j] = *(const bf16x8*)&Bs[(wn + j * 16 + l15) * 64 + c];
#pragma unroll
      for (int i = 0; i < 4; i++)
#pragma unroll
        for (int j = 0; j < 4; j++) acc[i][j] = MFMA(af[i], bfr[j], acc[i][j]);
    }
    __syncthreads();
  }
}

// -------- fused QKV GEMM over N=3072; Q,K -> [B,S,D]; V -> [B,H,DH,VTS] --------
__global__ __launch_bounds__(256, 3) void k_gemm_qkv(
    const u16* __restrict__ xb, const u16* __restrict__ wqkvt,
    const float* __restrict__ bq, const float* __restrict__ bk_, const float* __restrict__ bv,
    u16* __restrict__ Qg, u16* __restrict__ Kg, u16* __restrict__ Vt) {
  __shared__ __align__(16) u16 smem[17408];   // stage: 2x8192; epilogue: 128x136
  u16* As = smem;
  u16* Bs = smem + 8192;
  const int L = blockIdx.x;
  const int xcd = L & 7, slot = L >> 3;            // slot 0..95
  const int mblk = (xcd >> 1) * 8 + (slot & 7);    // 0..31
  const int nblk = (xcd & 1) * 12 + (slot >> 3);   // 0..23
  const int n0 = nblk * 128, m0 = mblk * 128;
  const int z = n0 >> 10;
  const float* bias = z == 0 ? bq : z == 1 ? bk_ : bv;
  f32x4 acc[4][4] = {};
  gemm_core128(xb, wqkvt, As, Bs, acc, m0, n0);

  const int tid = threadIdx.x;
  const int w = tid >> 6, lane = tid & 63;
  const int quad = lane >> 4, l15 = lane & 15;
  const int wm = (w & 1) * 64, wn = (w >> 1) * 64;
  const int nloc = n0 & 1023;
  float biasv[4];
#pragma unroll
  for (int j = 0; j < 4; j++) biasv[j] = bias[nloc + wn + j * 16 + l15];
  const int b_ = m0 >> 11, sb = m0 & 2047;
  // Q pre-scale folds 1/sqrt(DH) and log2(e) so attention uses raw exp2.
  const float scale = z == 0 ? 0.125f * 1.44269504f : 1.0f;
  const int row = tid >> 4, ch = tid & 15;

  if (z < 2) {
    // C-layout -> LDS (padded stride 136) -> coalesced row-major store
#pragma unroll
    for (int j = 0; j < 4; j++)
#pragma unroll
      for (int i = 0; i < 4; i++)
#pragma unroll
        for (int r = 0; r < 4; r++)
          smem[(wm + i * 16 + quad * 4 + r) * 136 + wn + j * 16 + l15] =
              f2b((acc[i][j][r] + biasv[j]) * scale);
    __syncthreads();
    u16* OG = z == 0 ? Qg : Kg;
#pragma unroll
    for (int it = 0; it < 8; it++) {
      int rr = row + it * 16;
      bf16x8 v = *(const bf16x8*)&smem[rr * 136 + ch * 8];
      *(bf16x8*)(OG + (size_t)(m0 + rr) * D_ + nloc + ch * 8) = v;
    }
  } else {
    // write transposed into LDS: Ct[n_local][m_local]
#pragma unroll
    for (int j = 0; j < 4; j++)
#pragma unroll
      for (int i = 0; i < 4; i++)
#pragma unroll
        for (int r = 0; r < 4; r++)
          smem[(wn + j * 16 + l15) * 136 + wm + i * 16 + quad * 4 + r] =
              f2b(acc[i][j][r] + biasv[j]);
    __syncthreads();
#pragma unroll
    for (int it = 0; it < 8; it++) {
      int nn = nloc + row + it * 16;
      int h = nn >> 6, dh = nn & 63;
      bf16x8 v = *(const bf16x8*)&smem[(row + it * 16) * 136 + ch * 8];
      *(bf16x8*)(Vt + ((size_t)(b_ * H_ + h) * DH_ + dh) * VTS + sb + ch * 8) = v;
    }
  }
}

// ---------- output projection: 64x128 tiles, BK=128 (32 MFMA/barrier) ----------
__global__ __launch_bounds__(256, 2) void k_gemm_out(
    const u16* __restrict__ Ab, const u16* __restrict__ wot,
    const float* __restrict__ bo, float* __restrict__ out) {
  __shared__ __align__(16) u16 smem[24576];   // A 64x128 + B 128x128; epilogue 64x136
  u16* As = smem;
  u16* Bs = smem + 8192;
  const int L = blockIdx.x;
  const int xcd = L & 7, slot = L >> 3;        // slot 0..63
  const int mblk = xcd * 8 + (slot & 7);       // 0..63
  const int nblk = slot >> 3;                  // 0..7
  const int n0 = nblk * 128, m0 = mblk * 64;
  const int tid = threadIdx.x;
  const int w = tid >> 6, lane = tid & 63;
  const int quad = lane >> 4, l15 = lane & 15;
  const int wn = w * 32;
  const int rowa = tid >> 4;                   // 0..15
  const int gg = (tid & 15) ^ rowa;
  const u16* ap = Ab + (size_t)(m0 + rowa) * D_ + gg * 8;
  const u16* bp = wot + (size_t)(n0 + rowa) * D_ + gg * 8;
  u16* As0 = As + w * 512;
  u16* Bs0 = Bs + w * 512;
  f32x4 acc[4][2] = {};
  for (int kb = 0; kb < D_; kb += 128) {
#pragma unroll
    for (int i = 0; i < 4; i++)
      async_cp16(ap + kb + (size_t)(i * 16) * D_, As0 + i * 2048);
#pragma unroll
    for (int i = 0; i < 8; i++)
      async_cp16(bp + kb + (size_t)(i * 16) * D_, Bs0 + i * 2048);
    __syncthreads();
#pragma unroll
    for (int kh = 0; kh < 4; kh++) {
      const int cs = (((quad + 4 * kh) ^ l15) * 8);
      bf16x8 af[4], bfr[2];
#pragma unroll
      for (int i = 0; i < 4; i++) af[i] = *(const bf16x8*)&As[(i * 16 + l15) * 128 + cs];
#pragma unroll
      for (int j = 0; j < 2; j++) bfr[j] = *(const bf16x8*)&Bs[(wn + j * 16 + l15) * 128 + cs];
#pragma unroll
      for (int i = 0; i < 4; i++)
#pragma unroll
        for (int j = 0; j < 2; j++) acc[i][j] = MFMA(af[i], bfr[j], acc[i][j]);
    }
    __syncthreads();
  }
  float biasv[2];
#pragma unroll
  for (int j = 0; j < 2; j++) biasv[j] = bo[n0 + wn + j * 16 + l15];
#pragma unroll
  for (int j = 0; j < 2; j++)
#pragma unroll
    for (int i = 0; i < 4; i++)
#pragma unroll
      for (int r = 0; r < 4; r++)
        smem[(i * 16 + quad * 4 + r) * 136 + wn + j * 16 + l15] = f2b(acc[i][j][r] + biasv[j]);
  __syncthreads();
  const int row = tid >> 4, ch = tid & 15;
#pragma unroll
  for (int it = 0; it < 4; it++) {
    int rr = row + it * 16;
    bf16x8 v = *(const bf16x8*)&smem[rr * 136 + ch * 8];
    float4 f0, f1;
    f0.x = b2f((u16)v[0]); f0.y = b2f((u16)v[1]); f0.z = b2f((u16)v[2]); f0.w = b2f((u16)v[3]);
    f1.x = b2f((u16)v[4]); f1.y = b2f((u16)v[5]); f1.z = b2f((u16)v[6]); f1.w = b2f((u16)v[7]);
    float* dst = out + (size_t)(m0 + rr) * D_ + n0 + ch * 8;
    *(float4*)dst = f0;
    *(float4*)(dst + 4) = f1;
  }
}

// ---------------- windowed flash attention, transposed-MFMA + pipelined ----------------
// R11: explicit 2-stage software pipeline — K/V frags for tile t+1 load at the
// TOP of iteration t, before any compute consumes tile t. One tile of MFMA+VALU
// (~500 cy) overlaps each load's L2/LLC latency. +32 VGPR for next-frags.
__global__ __launch_bounds__(256, 4) void k_attn(
    const u16* __restrict__ Qg, const u16* __restrict__ Kg,
    const u16* __restrict__ Vt, u16* __restrict__ Ab) {
  __shared__ __align__(16) u16 Plds[4][16 * 72];
  const int tid = threadIdx.x;
  const int w = tid >> 6, lane = tid & 63;
  const int quad = lane >> 4, l15 = lane & 15;
  const int bh = blockIdx.x;
  const int qw = blockIdx.y * 64 + w * 16;
  const int b_ = bh >> 4, h = bh & 15;

  // Q fragment: lane = query, quad*8 dh chunk (pre-scaled by 0.125*log2e)
  const u16* Qbase = Qg + (size_t)(b_ * S_ + qw + l15) * D_ + h * DH_ + quad * 8;
  bf16x8 aq0 = *(const bf16x8*)Qbase;
  bf16x8 aq1 = *(const bf16x8*)(Qbase + 32);

  float lr = 0.f;
  f32x4 Oacc[4] = {};

  const u16* Kb = Kg + (size_t)b_ * S_ * D_ + h * DH_ + quad * 8;
  const u16* Vb = Vt + (size_t)bh * DH_ * VTS + (size_t)l15 * VTS + quad * 8;
  const int klo = qw >= WIN_ ? ((qw - WIN_) & ~31) : 0;
  const int q = qw + l15;
  const int srcA = l15 + ((quad & 1) ? 32 : 0);
  const int srcB = srcA + 16;

  bf16x8 k00, k01, k10, k11, v0, v1, v2, v3;
  {
    const u16* Kt0 = Kb + (size_t)(klo + l15) * D_;
    k00 = *(const bf16x8*)Kt0;
    k01 = *(const bf16x8*)(Kt0 + 32);
    k10 = *(const bf16x8*)(Kt0 + (size_t)16 * D_);
    k11 = *(const bf16x8*)(Kt0 + (size_t)16 * D_ + 32);
    const u16* Vt0 = Vb + klo;
    v0 = *(const bf16x8*)(Vt0);
    v1 = *(const bf16x8*)(Vt0 + (size_t)16 * VTS);
    v2 = *(const bf16x8*)(Vt0 + (size_t)32 * VTS);
    v3 = *(const bf16x8*)(Vt0 + (size_t)48 * VTS);
  }

  for (int k0 = klo;;) {
    const int kn = k0 + 32;
    const bool more = kn < qw + 16;   // wave-uniform
    bf16x8 nk00, nk01, nk10, nk11, nv0, nv1, nv2, nv3;
    if (more) {
      // prefetch tile t+1 — issued before any use of tile t's frags
      const u16* Kt0 = Kb + (size_t)(kn + l15) * D_;
      nk00 = *(const bf16x8*)Kt0;
      nk01 = *(const bf16x8*)(Kt0 + 32);
      nk10 = *(const bf16x8*)(Kt0 + (size_t)16 * D_);
      nk11 = *(const bf16x8*)(Kt0 + (size_t)16 * D_ + 32);
      const u16* Vt0 = Vb + kn;
      nv0 = *(const bf16x8*)(Vt0);
      nv1 = *(const bf16x8*)(Vt0 + (size_t)16 * VTS);
      nv2 = *(const bf16x8*)(Vt0 + (size_t)32 * VTS);
      nv3 = *(const bf16x8*)(Vt0 + (size_t)48 * VTS);
    }

    // S^T: col=lane=query, row=quad*4+r=key-offset
    f32x4 s0 = {0.f, 0.f, 0.f, 0.f}, s1 = {0.f, 0.f, 0.f, 0.f};
    s0 = MFMA(k00, aq0, s0);
    s0 = MFMA(k01, aq1, s0);
    s1 = MFMA(k10, aq0, s1);
    s1 = MFMA(k11, aq1, s1);

    float e[8];
#pragma unroll
    for (int r = 0; r < 4; r++) {
      int key0 = k0 + quad * 4 + r;
      int key1 = key0 + 16;
      float p0 = (key0 <= q && key0 + WIN_ >= q) ? __builtin_amdgcn_exp2f(s0[r]) : 0.f;
      float p1 = (key1 <= q && key1 + WIN_ >= q) ? __builtin_amdgcn_exp2f(s1[r]) : 0.f;
      e[r] = p0; e[4 + r] = p1;
      lr += p0 + p1;
    }
    // pack exp values to bf16 pairs, then cross-lane transpose into P^T B-frag
    unsigned int s0p01 = (unsigned)f2b(e[0]) | ((unsigned)f2b(e[1]) << 16);
    unsigned int s0p23 = (unsigned)f2b(e[2]) | ((unsigned)f2b(e[3]) << 16);
    unsigned int s1p01 = (unsigned)f2b(e[4]) | ((unsigned)f2b(e[5]) << 16);
    unsigned int s1p23 = (unsigned)f2b(e[6]) | ((unsigned)f2b(e[7]) << 16);
    unsigned int a0 = (unsigned)__shfl((int)s0p01, srcA);
    unsigned int a1 = (unsigned)__shfl((int)s0p23, srcA);
    unsigned int a2 = (unsigned)__shfl((int)s0p01, srcB);
    unsigned int a3 = (unsigned)__shfl((int)s0p23, srcB);
    unsigned int c0 = (unsigned)__shfl((int)s1p01, srcA);
    unsigned int c1 = (unsigned)__shfl((int)s1p23, srcA);
    unsigned int c2 = (unsigned)__shfl((int)s1p01, srcB);
    unsigned int c3 = (unsigned)__shfl((int)s1p23, srcB);
    union { unsigned int u[4]; bf16x8 v; } pf;
    const bool lo = quad < 2;
    pf.u[0] = lo ? a0 : c0;
    pf.u[1] = lo ? a1 : c1;
    pf.u[2] = lo ? a2 : c2;
    pf.u[3] = lo ? a3 : c3;

    // O^T += V^T · P^T : col=lane=query, row=dh-within-group
    Oacc[0] = MFMA(v0, pf.v, Oacc[0]);
    Oacc[1] = MFMA(v1, pf.v, Oacc[1]);
    Oacc[2] = MFMA(v2, pf.v, Oacc[2]);
    Oacc[3] = MFMA(v3, pf.v, Oacc[3]);

    if (!more) break;
    k00 = nk00; k01 = nk01; k10 = nk10; k11 = nk11;
    v0 = nv0; v1 = nv1; v2 = nv2; v3 = nv3;
    k0 = kn;
  }

  // lr per lane covers this quad's key rows; sum across quads (same l15)
  lr += __shfl_xor(lr, 16);
  lr += __shfl_xor(lr, 32);
  const float inv = 1.0f / lr;

  // epilogue: lane=query holds dh=j*16+quad*4+r -> LDS row l15 -> coalesced store
  u16* P = &Plds[w][0];
#pragma unroll
  for (int j = 0; j < 4; j++)
#pragma unroll
    for (int r = 0; r < 4; r++)
      P[l15 * 72 + j * 16 + quad * 4 + r] = f2b(Oacc[j][r] * inv);
  {
    int rq = lane >> 2, cc = lane & 3;
    bf16x8 ov0 = *(const bf16x8*)&P[rq * 72 + cc * 16];
    bf16x8 ov1 = *(const bf16x8*)&P[rq * 72 + cc * 16 + 8];
    u16* dst = Ab + (size_t)(b_ * S_ + qw + rq) * D_ + h * DH_ + cc * 16;
    *(bf16x8*)dst = ov0;
    *(bf16x8*)(dst + 8) = ov1;
  }
}

extern "C" void kernel_launch(void* const* d_in, const int* in_sizes, int n_in,
                              void* d_out, int out_size, void* d_ws, size_t ws_size,
                              hipStream_t stream) {
  const float* x  = (const float*)d_in[0];
  const float* wq = (const float*)d_in[1];
  const float* bq = (const float*)d_in[2];
  const float* wk = (const float*)d_in[3];
  const float* bk = (const float*)d_in[4];
  const float* wv = (const float*)d_in[5];
  const float* bv = (const float*)d_in[6];
  const float* wo = (const float*)d_in[7];
  const float* bo = (const float*)d_in[8];

  char* ws = (char*)d_ws;
  const size_t MB = 1u << 20;
  u16* Qg    = (u16*)(ws + 0 * MB);    // 8 MB [B,S,D] bf16, pre-scaled
  u16* Kg    = (u16*)(ws + 8 * MB);    // 8 MB [B,S,D]
  u16* Vt    = (u16*)(ws + 16 * MB);   // 9 MB [B,H,DH,VTS] (padded stride)
  u16* Ab    = (u16*)(ws + 25 * MB);   // 8 MB [B,S,D] attention output
  u16* xb    = (u16*)(ws + 33 * MB);   // 8 MB [B*S,D]
  u16* wqkvt = (u16*)(ws + 41 * MB);   // 6 MB [3072][1024] transposed bf16
  u16* wot   = (u16*)(ws + 47 * MB);   // 2 MB [1024][1024] transposed bf16

  k_prep<<<5120, 256, 0, stream>>>(x, wq, wk, wv, wo, xb, wqkvt, wot);
  k_gemm_qkv<<<768, 256, 0, stream>>>(xb, wqkvt, bq, bk, bv, Qg, Kg, Vt);
  k_attn<<<dim3(32, 32), 256, 0, stream>>>(Qg, Kg, Vt, Ab);
  k_gemm_out<<<512, 256, 0, stream>>>(Ab, wot, bo, (float*)d_out);
}